// Round 1
// baseline (894.276 us; speedup 1.0000x reference)
//
#include <hip/hip_runtime.h>
#include <math.h>

#define NTOK 65536
#define LSEQ 16384
#define BATCH 4
#define GCH 64
#define NCH 256   // LSEQ / GCH

// ---------------- K0a: scalar SSM parameter setup (fp64) ----------------
__global__ void setup_scalar_k(const float* __restrict__ A_real, const float* __restrict__ A_imag,
                               const float* __restrict__ inv_dt,
                               float2* __restrict__ dAf, float2* __restrict__ fvec,
                               float2* __restrict__ powt) {
  int p = threadIdx.x;
  if (p >= 64) return;
  double ar = (double)A_real[p], ai = (double)A_imag[p];
  double dt = log1p(exp((double)inv_dt[p]));   // softplus, inv_dt < 0 so safe
  double zr = 0.5 * dt * ar, zi = 0.5 * dt * ai;
  double d1r = 1.0 - zr;
  double den = d1r * d1r + zi * zi;
  double blr = d1r / den, bli = zi / den;      // BL = 1/(1-z)
  double nr = 1.0 + zr, ni = zi;               // 1+z
  double dar = blr * nr - bli * ni;            // dA = BL*(1+z)
  double dai = blr * ni + bli * nr;
  dAf[p] = make_float2((float)dar, (float)dai);
  fvec[p] = make_float2((float)(blr * dt), (float)(bli * dt));   // f = BL*dt
  double cr = 1.0, ci = 0.0;
  for (int k = 0; k <= GCH; ++k) {
    powt[p * (GCH + 1) + k] = make_float2((float)cr, (float)ci); // dA^k
    double t = cr * dar - ci * dai;
    ci = cr * dai + ci * dar;
    cr = t;
  }
}

// ---------------- K0b: build dB^T (512x128) and Ccat^T (128x512) ----------------
__global__ void setup_tables_k(const float* __restrict__ B_re, const float* __restrict__ B_im,
                               const float* __restrict__ C_re, const float* __restrict__ C_im,
                               const float2* __restrict__ fvec,
                               float* __restrict__ dBT, float* __restrict__ CcT) {
  int idx = blockIdx.x * blockDim.x + threadIdx.x;
  int stride = gridDim.x * blockDim.x;
  for (int i = idx; i < 64 * 512; i += stride) {
    int p = i >> 9, d = i & 511;
    float2 f = fvec[p];
    float br = B_re[p * 512 + d], bi = B_im[p * 512 + d];
    dBT[d * 128 + p]      = f.x * br - f.y * bi;   // Re(dB)
    dBT[d * 128 + 64 + p] = f.x * bi + f.y * br;   // Im(dB)
  }
  for (int i = idx; i < 128 * 512; i += stride) {
    int k = i >> 9, d = i & 511;
    CcT[i] = (k < 64) ? C_re[d * 64 + k] : -C_im[d * 64 + (k - 64)];
  }
}

// ---------------- SGEMM: 128x128 tile, BK=16, 8x8 per thread ----------------
// MODE 0: C = silu(A@B), split cols [0,512) -> C0 (u), [512,1024) -> C1 (sres)
// MODE 1: C0 = A@B
// MODE 2: y = A@B + Dvec*C0 ; C1 <- y * C1   (C0=u read, C1=sres read-modify-write)
template<int MODE>
__global__ __launch_bounds__(256) void sgemm128(
    const float* __restrict__ A, const float* __restrict__ B,
    float* __restrict__ C0, float* __restrict__ C1,
    const float* __restrict__ Dvec, int M, int K, int N) {
  __shared__ float As[16][132];
  __shared__ float Bs[16][132];
  const int tid = threadIdx.x;
  const int tx = tid & 15, ty = tid >> 4;
  const int m0 = blockIdx.x * 128, n0 = blockIdx.y * 128;
  float acc[8][8];
#pragma unroll
  for (int i = 0; i < 8; ++i)
#pragma unroll
    for (int j = 0; j < 8; ++j) acc[i][j] = 0.f;

  const int arow = tid >> 1;           // 0..127
  const int ak = (tid & 1) * 4;        // 0 or 4 (and +8)
  const int brow = tid >> 4;           // 0..15
  const int bc = (tid & 15) * 4;       // 0..60 (and +64)
  const float* Aptr = A + (size_t)(m0 + arow) * K;

  for (int k0 = 0; k0 < K; k0 += 16) {
    float4 a0 = *(const float4*)(Aptr + k0 + ak);
    float4 a1 = *(const float4*)(Aptr + k0 + ak + 8);
    float4 b0 = *(const float4*)(B + (size_t)(k0 + brow) * N + n0 + bc);
    float4 b1 = *(const float4*)(B + (size_t)(k0 + brow) * N + n0 + bc + 64);
    __syncthreads();
    As[ak + 0][arow] = a0.x; As[ak + 1][arow] = a0.y; As[ak + 2][arow] = a0.z; As[ak + 3][arow] = a0.w;
    As[ak + 8][arow] = a1.x; As[ak + 9][arow] = a1.y; As[ak + 10][arow] = a1.z; As[ak + 11][arow] = a1.w;
    *(float4*)&Bs[brow][bc] = b0;
    *(float4*)&Bs[brow][bc + 64] = b1;
    __syncthreads();
#pragma unroll
    for (int k = 0; k < 16; ++k) {
      float4 aA = *(const float4*)&As[k][ty * 4];
      float4 aB = *(const float4*)&As[k][ty * 4 + 64];
      float4 bA = *(const float4*)&Bs[k][tx * 4];
      float4 bB = *(const float4*)&Bs[k][tx * 4 + 64];
      float av[8] = {aA.x, aA.y, aA.z, aA.w, aB.x, aB.y, aB.z, aB.w};
      float bv[8] = {bA.x, bA.y, bA.z, bA.w, bB.x, bB.y, bB.z, bB.w};
#pragma unroll
      for (int i = 0; i < 8; ++i)
#pragma unroll
        for (int j = 0; j < 8; ++j)
          acc[i][j] = fmaf(av[i], bv[j], acc[i][j]);
    }
  }

#pragma unroll
  for (int i = 0; i < 8; ++i) {
    int m = m0 + ((i < 4) ? (ty * 4 + i) : (64 + ty * 4 + i - 4));
#pragma unroll
    for (int jh = 0; jh < 2; ++jh) {
      int cbase = n0 + jh * 64 + tx * 4;
      if (MODE == 0) {
#pragma unroll
        for (int j = 0; j < 4; ++j) {
          float v = acc[i][jh * 4 + j];
          float s = v / (1.f + __expf(-v));
          int col = cbase + j;
          if (col < 512) C0[(size_t)m * 512 + col] = s;
          else           C1[(size_t)m * 512 + col - 512] = s;
        }
      } else if (MODE == 1) {
        float4 v;
        v.x = acc[i][jh * 4 + 0]; v.y = acc[i][jh * 4 + 1];
        v.z = acc[i][jh * 4 + 2]; v.w = acc[i][jh * 4 + 3];
        *(float4*)&C0[(size_t)m * N + cbase] = v;
      } else {
#pragma unroll
        for (int j = 0; j < 4; ++j) {
          int col = cbase + j;
          float uu = C0[(size_t)m * 512 + col];
          float sr = C1[(size_t)m * 512 + col];
          float yv = acc[i][jh * 4 + j] + Dvec[col] * uu;
          C1[(size_t)m * 512 + col] = yv * sr;
        }
      }
    }
  }
}

// ---------------- K3a: per-chunk local inclusive scan (in place on Bu) ----------------
__global__ __launch_bounds__(256) void scan_local_k(float* __restrict__ Bu, const float2* __restrict__ dAf) {
  int unit = blockIdx.x * 4 + (threadIdx.x >> 6);   // 0..1023 = b*NCH + c
  int p = threadIdx.x & 63;
  int b = unit >> 8, c = unit & 255;
  float2 dA = dAf[p];
  size_t base = ((size_t)b * LSEQ + (size_t)c * GCH) * 128;
  float hr = 0.f, hi = 0.f;
  for (int i0 = 0; i0 < GCH; i0 += 8) {
    float br[8], bi[8];
#pragma unroll
    for (int j = 0; j < 8; ++j) {
      br[j] = Bu[base + (size_t)(i0 + j) * 128 + p];
      bi[j] = Bu[base + (size_t)(i0 + j) * 128 + 64 + p];
    }
#pragma unroll
    for (int j = 0; j < 8; ++j) {
      float nr = fmaf(dA.x, hr, fmaf(-dA.y, hi, br[j]));
      float ni = fmaf(dA.x, hi, fmaf(dA.y, hr, bi[j]));
      hr = nr; hi = ni; br[j] = hr; bi[j] = hi;
    }
#pragma unroll
    for (int j = 0; j < 8; ++j) {
      Bu[base + (size_t)(i0 + j) * 128 + p] = br[j];
      Bu[base + (size_t)(i0 + j) * 128 + 64 + p] = bi[j];
    }
  }
}

// ---------------- K3b: chunk-carry prefix scan ----------------
__global__ void scan_carry_k(const float* __restrict__ Bu, float* __restrict__ offc,
                             const float2* __restrict__ powt) {
  int b = threadIdx.x >> 6;   // 0..3
  int p = threadIdx.x & 63;
  float2 dAG = powt[p * (GCH + 1) + GCH];   // dA^G
  float rr = 0.f, ri = 0.f;
  for (int c = 0; c < NCH; ++c) {
    size_t orow = (size_t)(b * NCH + c) * 128;
    offc[orow + p] = rr;
    offc[orow + 64 + p] = ri;
    size_t n = (size_t)b * LSEQ + (size_t)c * GCH + (GCH - 1);
    float er = Bu[n * 128 + p], ei = Bu[n * 128 + 64 + p];
    float nr = fmaf(dAG.x, rr, fmaf(-dAG.y, ri, er));
    float ni = fmaf(dAG.x, ri, fmaf(dAG.y, rr, ei));
    rr = nr; ri = ni;
  }
}

// ---------------- K3c: fixup h = local + dA^{i+1} * offset ----------------
__global__ __launch_bounds__(256) void fixup_k(float* __restrict__ Bu, const float* __restrict__ offc,
                                               const float2* __restrict__ powt) {
  size_t idx = (size_t)blockIdx.x * blockDim.x + threadIdx.x;
  const size_t total = (size_t)NTOK * 64;
  size_t stride = (size_t)gridDim.x * blockDim.x;
  for (; idx < total; idx += stride) {
    int p = (int)(idx & 63);
    size_t n = idx >> 6;
    int l = (int)(n & (LSEQ - 1));
    int i = l & (GCH - 1);
    float2 pw = powt[p * (GCH + 1) + i + 1];
    size_t crow = (n >> 6) * 128;
    float orr = offc[crow + p], oii = offc[crow + 64 + p];
    Bu[n * 128 + p]      += pw.x * orr - pw.y * oii;
    Bu[n * 128 + 64 + p] += pw.x * oii + pw.y * orr;
  }
}

extern "C" void kernel_launch(void* const* d_in, const int* in_sizes, int n_in,
                              void* d_out, int out_size, void* d_ws, size_t ws_size,
                              hipStream_t stream) {
  const float* x      = (const float*)d_in[0];
  const float* W_in   = (const float*)d_in[1];
  const float* W_out  = (const float*)d_in[2];
  const float* A_real = (const float*)d_in[3];
  const float* A_imag = (const float*)d_in[4];
  const float* B_re   = (const float*)d_in[5];
  const float* B_im   = (const float*)d_in[6];
  const float* C_re   = (const float*)d_in[7];
  const float* C_im   = (const float*)d_in[8];
  const float* Dv     = (const float*)d_in[9];
  const float* inv_dt = (const float*)d_in[10];

  // ws: u (N x 512) + sres (N x 512), fp32 -> 256 MiB
  float* u    = (float*)d_ws;
  float* sres = u + (size_t)NTOK * 512;

  // d_out doubles as scratch for Bu/h + small tables; fully overwritten by final GEMM
  float* O    = (float*)d_out;
  float* Bu   = O;                        // N*128 = 8388608 floats
  float* offc = O + 8388608;              // 1024*128 = 131072
  float* dBT  = O + 8519680;              // 512*128 = 65536
  float* CcT  = O + 8585216;              // 128*512 = 65536
  float2* powt = (float2*)(O + 8650752);  // 64*65 float2
  float2* dAf  = (float2*)(O + 8659072);  // 64 float2
  float2* fvec = (float2*)(O + 8659200);  // 64 float2

  setup_scalar_k<<<1, 64, 0, stream>>>(A_real, A_imag, inv_dt, dAf, fvec, powt);
  setup_tables_k<<<128, 256, 0, stream>>>(B_re, B_im, C_re, C_im, fvec, dBT, CcT);

  // K1: in-proj + silu split
  sgemm128<0><<<dim3(512, 8), 256, 0, stream>>>(x, W_in, u, sres, nullptr, NTOK, 256, 1024);
  // K2: Bu = u @ dB^T (re|im)
  sgemm128<1><<<dim3(512, 1), 256, 0, stream>>>(u, dBT, Bu, nullptr, nullptr, NTOK, 512, 128);
  // K3: chunked scan
  scan_local_k<<<256, 256, 0, stream>>>(Bu, dAf);
  scan_carry_k<<<1, 256, 0, stream>>>(Bu, offc, powt);
  fixup_k<<<4096, 256, 0, stream>>>(Bu, offc, powt);
  // K4a: y = Re(h C^T) + D*u, gate by sres (writes g into sres plane)
  sgemm128<2><<<dim3(512, 4), 256, 0, stream>>>(Bu, CcT, u, sres, Dv, NTOK, 128, 512);
  // K4b: out = g @ W_out
  sgemm128<1><<<dim3(512, 2), 256, 0, stream>>>(sres, W_out, O, nullptr, nullptr, NTOK, 512, 256);
}

// Round 2
// 279.038 us; speedup vs baseline: 3.2049x; 3.2049x over previous
//
#include <hip/hip_runtime.h>
#include <math.h>

#define NTOK 65536
#define LSEQ 16384
#define GCH 64
#define NCH 256   // LSEQ / GCH

typedef __attribute__((ext_vector_type(8))) short short8v;
typedef __attribute__((ext_vector_type(4))) float f32x4;
typedef unsigned short u16;

__device__ __forceinline__ u16 f2bf(float f) {
  unsigned u = __float_as_uint(f);
  return (u16)((u + 0x7FFFu + ((u >> 16) & 1u)) >> 16);
}
__device__ __forceinline__ float bf2f(u16 b) {
  return __uint_as_float(((unsigned)b) << 16);
}
__device__ __forceinline__ void gld16(const u16* g, u16* l) {
  __builtin_amdgcn_global_load_lds((const __attribute__((address_space(1))) void*)g,
                                   (__attribute__((address_space(3))) void*)l, 16, 0, 0);
}

// ---------------- K0a: scalar SSM parameter setup (fp64) ----------------
__global__ void setup_scalar_k(const float* __restrict__ A_real, const float* __restrict__ A_imag,
                               const float* __restrict__ inv_dt,
                               float2* __restrict__ dAf, float2* __restrict__ fvec,
                               float2* __restrict__ powt) {
  int p = threadIdx.x;
  if (p >= 64) return;
  double ar = (double)A_real[p], ai = (double)A_imag[p];
  double dt = log1p(exp((double)inv_dt[p]));   // softplus
  double zr = 0.5 * dt * ar, zi = 0.5 * dt * ai;
  double d1r = 1.0 - zr;
  double den = d1r * d1r + zi * zi;
  double blr = d1r / den, bli = zi / den;      // BL = 1/(1-z)
  double nr = 1.0 + zr, ni = zi;               // 1+z
  double dar = blr * nr - bli * ni;            // dA
  double dai = blr * ni + bli * nr;
  dAf[p] = make_float2((float)dar, (float)dai);
  fvec[p] = make_float2((float)(blr * dt), (float)(bli * dt));   // f = BL*dt
  double cr = 1.0, ci = 0.0;
  for (int k = 0; k <= GCH; ++k) {
    powt[p * (GCH + 1) + k] = make_float2((float)cr, (float)ci); // dA^k
    double t = cr * dar - ci * dai;
    ci = cr * dai + ci * dar;
    cr = t;
  }
}

// ---------------- K0b: build bf16 B^T-layout weight tables ----------------
__global__ void setup_tables_k(const float* __restrict__ B_re, const float* __restrict__ B_im,
                               const float* __restrict__ C_re, const float* __restrict__ C_im,
                               const float* __restrict__ W_in, const float* __restrict__ W_out,
                               const float2* __restrict__ fvec,
                               u16* __restrict__ WinT, u16* __restrict__ dBn,
                               u16* __restrict__ Ccb, u16* __restrict__ WoutT) {
  int idx = blockIdx.x * blockDim.x + threadIdx.x;
  int stride = gridDim.x * blockDim.x;
  // WinT [1024][256]
  for (int i = idx; i < 1024 * 256; i += stride) {
    int n = i >> 8, k = i & 255;
    WinT[i] = f2bf(W_in[k * 1024 + n]);
  }
  // dBn [128][512]  (rows 0-63 Re(dB), 64-127 Im(dB))
  for (int i = idx; i < 128 * 512; i += stride) {
    int p = i >> 9, d = i & 511;
    float2 f = fvec[p & 63];
    float br = B_re[(p & 63) * 512 + d], bi = B_im[(p & 63) * 512 + d];
    float v = (p < 64) ? (f.x * br - f.y * bi) : (f.x * bi + f.y * br);
    dBn[i] = f2bf(v);
  }
  // Ccb [512][128]  (cols 0-63: C_re, 64-127: -C_im)
  for (int i = idx; i < 512 * 128; i += stride) {
    int d = i >> 7, k = i & 127;
    float v = (k < 64) ? C_re[d * 64 + k] : -C_im[d * 64 + (k - 64)];
    Ccb[i] = f2bf(v);
  }
  // WoutT [256][512]
  for (int i = idx; i < 256 * 512; i += stride) {
    int n = i >> 9, k = i & 511;
    WoutT[i] = f2bf(W_out[k * 256 + n]);
  }
}

// ---------------- x -> bf16 ----------------
__global__ __launch_bounds__(256) void cvt_x_k(const float* __restrict__ x, u16* __restrict__ xb) {
  size_t i = ((size_t)blockIdx.x * blockDim.x + threadIdx.x) * 4;
  size_t stride = (size_t)gridDim.x * blockDim.x * 4;
  const size_t total = (size_t)NTOK * 256;
  for (; i < total; i += stride) {
    float4 v = *(const float4*)(x + i);
    ushort4 o;
    o.x = f2bf(v.x); o.y = f2bf(v.y); o.z = f2bf(v.z); o.w = f2bf(v.w);
    *(ushort4*)(xb + i) = o;
  }
}

// ---------------- bf16 MFMA GEMM: 128x128 tile, BK=32, 4 waves (2x2) ----------------
// A [M][K] bf16, Bt [N][K] bf16 (B transposed). M,N multiples of 128; K multiple of 32.
// MODE 0: u/sres = silu(acc), split at col 512        (C0=u_bf, C1=sres_bf)
// MODE 1: C0(fp32)[m*128+n] = acc                     (Bu)
// MODE 2: g = (acc + D*u)*sres -> C1 (bf16, in place) (C0=u_bf, C1=sres_bf)
// MODE 3: C0(fp32)[m*256+n] = acc                     (final out)
template<int MODE>
__global__ __launch_bounds__(256) void mgemm(
    const u16* __restrict__ A, const u16* __restrict__ Bt,
    void* __restrict__ C0, void* __restrict__ C1,
    const float* __restrict__ Dvec, int K) {
  __shared__ u16 As[128 * 32];
  __shared__ u16 Bs[128 * 32];
  const int tid = threadIdx.x;
  const int w = tid >> 6, l = tid & 63;
  const int wm = w >> 1, wn = w & 1;
  const int m0 = blockIdx.x * 128, n0 = blockIdx.y * 128;

  f32x4 acc[4][4] = {};

  const int lr = l >> 2;           // row within 16-row chunk
  const int lc = (l & 3) * 8;      // k-elem offset (8 bf16 = 16B)
  const u16* gA = A + (size_t)(m0 + w * 32 + lr) * K + lc;
  const u16* gB = Bt + (size_t)(n0 + w * 32 + lr) * K + lc;
  u16* lAs = &As[w * 1024];        // (w*2+0)*1024B = w*1024 u16
  u16* lBs = &Bs[w * 1024];
  const size_t rowskip = (size_t)16 * K;

  const int kg = (l >> 4) * 8;
  const int fr = l & 15;

  for (int k0 = 0; k0 < K; k0 += 32) {
    gld16(gA + k0, lAs);
    gld16(gA + k0 + rowskip, lAs + 512);
    gld16(gB + k0, lBs);
    gld16(gB + k0 + rowskip, lBs + 512);
    asm volatile("s_waitcnt vmcnt(0)" ::: "memory");
    __syncthreads();
    short8v af[4], bfr[4];
#pragma unroll
    for (int mi = 0; mi < 4; ++mi)
      af[mi] = *(const short8v*)&As[(wm * 64 + mi * 16 + fr) * 32 + kg];
#pragma unroll
    for (int ni = 0; ni < 4; ++ni)
      bfr[ni] = *(const short8v*)&Bs[(wn * 64 + ni * 16 + fr) * 32 + kg];
#pragma unroll
    for (int mi = 0; mi < 4; ++mi)
#pragma unroll
      for (int ni = 0; ni < 4; ++ni)
        acc[mi][ni] = __builtin_amdgcn_mfma_f32_16x16x32_bf16(af[mi], bfr[ni], acc[mi][ni], 0, 0, 0);
    __syncthreads();
  }

  const int rbase = (l >> 4) * 4;
#pragma unroll
  for (int mi = 0; mi < 4; ++mi) {
#pragma unroll
    for (int ni = 0; ni < 4; ++ni) {
      int gr0 = m0 + wm * 64 + mi * 16 + rbase;
      int gc = n0 + wn * 64 + ni * 16 + fr;
#pragma unroll
      for (int j = 0; j < 4; ++j) {
        float v = acc[mi][ni][j];
        size_t r = (size_t)(gr0 + j);
        if (MODE == 0) {
          float s = v / (1.f + __expf(-v));
          if (gc < 512) ((u16*)C0)[r * 512 + gc] = f2bf(s);
          else          ((u16*)C1)[r * 512 + gc - 512] = f2bf(s);
        } else if (MODE == 1) {
          ((float*)C0)[r * 128 + gc] = v;
        } else if (MODE == 2) {
          float uu = bf2f(((const u16*)C0)[r * 512 + gc]);
          float sr = bf2f(((const u16*)C1)[r * 512 + gc]);
          float y = v + Dvec[gc] * uu;
          ((u16*)C1)[r * 512 + gc] = f2bf(y * sr);
        } else {
          ((float*)C0)[r * 256 + gc] = v;
        }
      }
    }
  }
}

// ---------------- K3a: per-chunk local inclusive scan (in place on Bu, fp32) ----------------
__global__ __launch_bounds__(256) void scan_local_k(float* __restrict__ Bu, const float2* __restrict__ dAf) {
  int unit = blockIdx.x * 4 + (threadIdx.x >> 6);   // b*NCH + c
  int p = threadIdx.x & 63;
  int b = unit >> 8, c = unit & 255;
  float2 dA = dAf[p];
  size_t base = ((size_t)b * LSEQ + (size_t)c * GCH) * 128;
  float hr = 0.f, hi = 0.f;
  for (int i0 = 0; i0 < GCH; i0 += 8) {
    float br[8], bi[8];
#pragma unroll
    for (int j = 0; j < 8; ++j) {
      br[j] = Bu[base + (size_t)(i0 + j) * 128 + p];
      bi[j] = Bu[base + (size_t)(i0 + j) * 128 + 64 + p];
    }
#pragma unroll
    for (int j = 0; j < 8; ++j) {
      float nr = fmaf(dA.x, hr, fmaf(-dA.y, hi, br[j]));
      float ni = fmaf(dA.x, hi, fmaf(dA.y, hr, bi[j]));
      hr = nr; hi = ni; br[j] = hr; bi[j] = hi;
    }
#pragma unroll
    for (int j = 0; j < 8; ++j) {
      Bu[base + (size_t)(i0 + j) * 128 + p] = br[j];
      Bu[base + (size_t)(i0 + j) * 128 + 64 + p] = bi[j];
    }
  }
}

// ---------------- K3b: chunk-carry prefix scan ----------------
__global__ void scan_carry_k(const float* __restrict__ Bu, float* __restrict__ offc,
                             const float2* __restrict__ powt) {
  int b = threadIdx.x >> 6;
  int p = threadIdx.x & 63;
  float2 dAG = powt[p * (GCH + 1) + GCH];   // dA^G
  float rr = 0.f, ri = 0.f;
  for (int c = 0; c < NCH; ++c) {
    size_t orow = (size_t)(b * NCH + c) * 128;
    offc[orow + p] = rr;
    offc[orow + 64 + p] = ri;
    size_t n = (size_t)b * LSEQ + (size_t)c * GCH + (GCH - 1);
    float er = Bu[n * 128 + p], ei = Bu[n * 128 + 64 + p];
    float nr = fmaf(dAG.x, rr, fmaf(-dAG.y, ri, er));
    float ni = fmaf(dAG.x, ri, fmaf(dAG.y, rr, ei));
    rr = nr; ri = ni;
  }
}

// ---------------- K3c: fixup h = local + dA^{i+1}*offset -> bf16 h ----------------
__global__ __launch_bounds__(256) void fixup_k(const float* __restrict__ Bu, const float* __restrict__ offc,
                                               const float2* __restrict__ powt, u16* __restrict__ hb) {
  size_t idx = (size_t)blockIdx.x * blockDim.x + threadIdx.x;
  const size_t total = (size_t)NTOK * 64;
  size_t stride = (size_t)gridDim.x * blockDim.x;
  for (; idx < total; idx += stride) {
    int p = (int)(idx & 63);
    size_t n = idx >> 6;
    int l = (int)(n & (LSEQ - 1));
    int i = l & (GCH - 1);
    float2 pw = powt[p * (GCH + 1) + i + 1];
    size_t crow = (n >> 6) * 128;
    float orr = offc[crow + p], oii = offc[crow + 64 + p];
    float hr = Bu[n * 128 + p]      + pw.x * orr - pw.y * oii;
    float hi = Bu[n * 128 + 64 + p] + pw.x * oii + pw.y * orr;
    hb[n * 128 + p] = f2bf(hr);
    hb[n * 128 + 64 + p] = f2bf(hi);
  }
}

extern "C" void kernel_launch(void* const* d_in, const int* in_sizes, int n_in,
                              void* d_out, int out_size, void* d_ws, size_t ws_size,
                              hipStream_t stream) {
  const float* x      = (const float*)d_in[0];
  const float* W_in   = (const float*)d_in[1];
  const float* W_out  = (const float*)d_in[2];
  const float* A_real = (const float*)d_in[3];
  const float* A_imag = (const float*)d_in[4];
  const float* B_re   = (const float*)d_in[5];
  const float* B_im   = (const float*)d_in[6];
  const float* C_re   = (const float*)d_in[7];
  const float* C_im   = (const float*)d_in[8];
  const float* Dv     = (const float*)d_in[9];
  const float* inv_dt = (const float*)d_in[10];

  // ---- workspace layout (bf16 buffers) ----
  u16* xb    = (u16*)d_ws;                       // N*256
  u16* u_bf  = xb + (size_t)NTOK * 256;          // N*512
  u16* sr_bf = u_bf + (size_t)NTOK * 512;        // N*512 (becomes g after K4a)
  u16* h_bf  = sr_bf + (size_t)NTOK * 512;       // N*128
  u16* WinT  = h_bf + (size_t)NTOK * 128;        // 1024*256
  u16* dBn   = WinT + 1024 * 256;                // 128*512
  u16* Ccb   = dBn + 128 * 512;                  // 512*128
  u16* WoutT = Ccb + 512 * 128;                  // 256*512

  // ---- d_out doubles as fp32 scratch (dead before final GEMM writes it) ----
  float* O    = (float*)d_out;
  float* Bu   = O;                        // N*128 = 8388608 floats
  float* offc = O + 8388608;              // 1024*128
  float2* powt = (float2*)(O + 8519680);  // 64*65 float2
  float2* dAf  = (float2*)(O + 8528000);  // 64 float2
  float2* fvec = (float2*)(O + 8528128);  // 64 float2

  setup_scalar_k<<<1, 64, 0, stream>>>(A_real, A_imag, inv_dt, dAf, fvec, powt);
  setup_tables_k<<<256, 256, 0, stream>>>(B_re, B_im, C_re, C_im, W_in, W_out, fvec,
                                          WinT, dBn, Ccb, WoutT);
  cvt_x_k<<<1024, 256, 0, stream>>>(x, xb);

  // K1: [u|res] = silu(x @ W_in)
  mgemm<0><<<dim3(512, 8), 256, 0, stream>>>(xb, WinT, u_bf, sr_bf, nullptr, 256);
  // K2: Bu = u @ dB^T (fp32 out)
  mgemm<1><<<dim3(512, 1), 256, 0, stream>>>(u_bf, dBn, Bu, nullptr, nullptr, 512);
  // K3: chunked scan (fp32), emits bf16 h
  scan_local_k<<<256, 256, 0, stream>>>(Bu, dAf);
  scan_carry_k<<<1, 256, 0, stream>>>(Bu, offc, powt);
  fixup_k<<<4096, 256, 0, stream>>>(Bu, offc, powt, h_bf);
  // K4a: g = (Re(h C^T) + D*u) * sres  (in place into sr_bf)
  mgemm<2><<<dim3(512, 4), 256, 0, stream>>>(h_bf, Ccb, u_bf, sr_bf, Dv, 128);
  // K4b: out = g @ W_out
  mgemm<3><<<dim3(512, 2), 256, 0, stream>>>(sr_bf, WoutT, O, nullptr, nullptr, 512);
}

// Round 3
// 260.545 us; speedup vs baseline: 3.4323x; 1.0710x over previous
//
#include <hip/hip_runtime.h>
#include <math.h>

#define NTOK 65536
#define LSEQ 16384
#define GCH 64
#define NCH 256   // LSEQ / GCH

typedef __attribute__((ext_vector_type(8))) short short8v;
typedef __attribute__((ext_vector_type(4))) float f32x4;
typedef unsigned short u16;

__device__ __forceinline__ u16 f2bf(float f) {
  unsigned u = __float_as_uint(f);
  return (u16)((u + 0x7FFFu + ((u >> 16) & 1u)) >> 16);
}
__device__ __forceinline__ float bf2f(u16 b) {
  return __uint_as_float(((unsigned)b) << 16);
}
__device__ __forceinline__ void gld16(const u16* g, u16* l) {
  __builtin_amdgcn_global_load_lds((const __attribute__((address_space(1))) void*)g,
                                   (__attribute__((address_space(3))) void*)l, 16, 0, 0);
}

// ---------------- K0a: scalar SSM parameter setup (fp64) ----------------
__global__ void setup_scalar_k(const float* __restrict__ A_real, const float* __restrict__ A_imag,
                               const float* __restrict__ inv_dt,
                               float2* __restrict__ dAf, float2* __restrict__ fvec,
                               float2* __restrict__ powt) {
  int p = threadIdx.x;
  if (p >= 64) return;
  double ar = (double)A_real[p], ai = (double)A_imag[p];
  double dt = log1p(exp((double)inv_dt[p]));   // softplus
  double zr = 0.5 * dt * ar, zi = 0.5 * dt * ai;
  double d1r = 1.0 - zr;
  double den = d1r * d1r + zi * zi;
  double blr = d1r / den, bli = zi / den;      // BL = 1/(1-z)
  double nr = 1.0 + zr, ni = zi;               // 1+z
  double dar = blr * nr - bli * ni;            // dA
  double dai = blr * ni + bli * nr;
  dAf[p] = make_float2((float)dar, (float)dai);
  fvec[p] = make_float2((float)(blr * dt), (float)(bli * dt));   // f = BL*dt
  double cr = 1.0, ci = 0.0;
  for (int k = 0; k <= GCH; ++k) {
    powt[p * (GCH + 1) + k] = make_float2((float)cr, (float)ci); // dA^k
    double t = cr * dar - ci * dai;
    ci = cr * dai + ci * dar;
    cr = t;
  }
}

// ---------------- K0b: build bf16 B^T-layout weight tables ----------------
__global__ void setup_tables_k(const float* __restrict__ B_re, const float* __restrict__ B_im,
                               const float* __restrict__ C_re, const float* __restrict__ C_im,
                               const float* __restrict__ W_in, const float* __restrict__ W_out,
                               const float2* __restrict__ fvec,
                               u16* __restrict__ WinT, u16* __restrict__ dBn,
                               u16* __restrict__ Ccb, u16* __restrict__ WoutT) {
  int idx = blockIdx.x * blockDim.x + threadIdx.x;
  int stride = gridDim.x * blockDim.x;
  // WinT [1024][256]
  for (int i = idx; i < 1024 * 256; i += stride) {
    int n = i >> 8, k = i & 255;
    WinT[i] = f2bf(W_in[k * 1024 + n]);
  }
  // dBn [128][512]  (rows 0-63 Re(dB), 64-127 Im(dB))
  for (int i = idx; i < 128 * 512; i += stride) {
    int p = i >> 9, d = i & 511;
    float2 f = fvec[p & 63];
    float br = B_re[(p & 63) * 512 + d], bi = B_im[(p & 63) * 512 + d];
    float v = (p < 64) ? (f.x * br - f.y * bi) : (f.x * bi + f.y * br);
    dBn[i] = f2bf(v);
  }
  // Ccb [512][128]  (cols 0-63: C_re, 64-127: -C_im)
  for (int i = idx; i < 512 * 128; i += stride) {
    int d = i >> 7, k = i & 127;
    float v = (k < 64) ? C_re[d * 64 + k] : -C_im[d * 64 + (k - 64)];
    Ccb[i] = f2bf(v);
  }
  // WoutT [256][512]
  for (int i = idx; i < 256 * 512; i += stride) {
    int n = i >> 9, k = i & 511;
    WoutT[i] = f2bf(W_out[k * 256 + n]);
  }
}

// ---------------- x -> bf16 ----------------
__global__ __launch_bounds__(256) void cvt_x_k(const float* __restrict__ x, u16* __restrict__ xb) {
  size_t i = ((size_t)blockIdx.x * blockDim.x + threadIdx.x) * 4;
  size_t stride = (size_t)gridDim.x * blockDim.x * 4;
  const size_t total = (size_t)NTOK * 256;
  for (; i < total; i += stride) {
    float4 v = *(const float4*)(x + i);
    ushort4 o;
    o.x = f2bf(v.x); o.y = f2bf(v.y); o.z = f2bf(v.z); o.w = f2bf(v.w);
    *(ushort4*)(xb + i) = o;
  }
}

// ---------------- bf16 MFMA GEMM: 128x128 tile, BK=32, 4 waves (2x2) ----------------
// A [M][K] bf16, Bt [N][K] bf16. LDS layout: per-row 4x 16B chunks, chunk
// index XOR-swizzled by (row&3) (source-side swizzle; gld_lds dest linear).
// 1D grid with bijective XCD swizzle; column tile = fastest after XCD chunking.
// MODE 0: u/sres = silu(acc), split at col 512        (C0=u_bf, C1=sres_bf)
// MODE 1: C0(fp32)[m*128+n] = acc                     (Bu)
// MODE 2: g = (acc + D*u)*sres -> C1 (bf16, in place) (C0=u_bf, C1=sres_bf)
// MODE 3: C0(fp32)[m*256+n] = acc                     (final out)
template<int MODE, int LOG_NBX>
__global__ __launch_bounds__(256) void mgemm(
    const u16* __restrict__ A, const u16* __restrict__ Bt,
    void* __restrict__ C0, void* __restrict__ C1,
    const float* __restrict__ Dvec, int K) {
  __shared__ u16 As[128 * 32];
  __shared__ u16 Bs[128 * 32];
  const int tid = threadIdx.x;
  const int w = tid >> 6, l = tid & 63;
  const int wm = w >> 1, wn = w & 1;

  // bijective XCD swizzle (gridDim.x % 8 == 0 for all our launches)
  const int lin = blockIdx.x;
  const int cpx = gridDim.x >> 3;
  const int swz = (lin & 7) * cpx + (lin >> 3);
  const int n0 = (swz & ((1 << LOG_NBX) - 1)) * 128;
  const int m0 = (swz >> LOG_NBX) * 128;

  f32x4 acc[4][4] = {};

  const int lr = l >> 2;                    // row 0..15 within 16-row chunk
  const int sc = (l & 3) ^ (lr & 3);        // swizzled source chunk
  const u16* gA = A + (size_t)(m0 + w * 32 + lr) * K + sc * 8;
  const u16* gB = Bt + (size_t)(n0 + w * 32 + lr) * K + sc * 8;
  u16* lAs = &As[w * 1024];
  u16* lBs = &Bs[w * 1024];
  const size_t rowskip = (size_t)16 * K;

  const int fr = l & 15;
  const int kgs = (((l >> 4) ^ (l & 3)) & 3) * 8;   // swizzled k-offset for frag reads

  for (int k0 = 0; k0 < K; k0 += 32) {
    gld16(gA + k0, lAs);
    gld16(gA + k0 + rowskip, lAs + 512);
    gld16(gB + k0, lBs);
    gld16(gB + k0 + rowskip, lBs + 512);
    asm volatile("s_waitcnt vmcnt(0)" ::: "memory");
    __syncthreads();
    short8v af[4], bfr[4];
#pragma unroll
    for (int mi = 0; mi < 4; ++mi)
      af[mi] = *(const short8v*)&As[(wm * 64 + mi * 16 + fr) * 32 + kgs];
#pragma unroll
    for (int ni = 0; ni < 4; ++ni)
      bfr[ni] = *(const short8v*)&Bs[(wn * 64 + ni * 16 + fr) * 32 + kgs];
#pragma unroll
    for (int mi = 0; mi < 4; ++mi)
#pragma unroll
      for (int ni = 0; ni < 4; ++ni)
        acc[mi][ni] = __builtin_amdgcn_mfma_f32_16x16x32_bf16(af[mi], bfr[ni], acc[mi][ni], 0, 0, 0);
    __syncthreads();
  }

  const int rbase = (l >> 4) * 4;
#pragma unroll
  for (int mi = 0; mi < 4; ++mi) {
#pragma unroll
    for (int ni = 0; ni < 4; ++ni) {
      int gr0 = m0 + wm * 64 + mi * 16 + rbase;
      int gc = n0 + wn * 64 + ni * 16 + fr;
#pragma unroll
      for (int j = 0; j < 4; ++j) {
        float v = acc[mi][ni][j];
        size_t r = (size_t)(gr0 + j);
        if (MODE == 0) {
          float s = v / (1.f + __expf(-v));
          if (gc < 512) ((u16*)C0)[r * 512 + gc] = f2bf(s);
          else          ((u16*)C1)[r * 512 + gc - 512] = f2bf(s);
        } else if (MODE == 1) {
          ((float*)C0)[r * 128 + gc] = v;
        } else if (MODE == 2) {
          float uu = bf2f(((const u16*)C0)[r * 512 + gc]);
          float sr = bf2f(((const u16*)C1)[r * 512 + gc]);
          float y = v + Dvec[gc] * uu;
          ((u16*)C1)[r * 512 + gc] = f2bf(y * sr);
        } else {
          ((float*)C0)[r * 256 + gc] = v;
        }
      }
    }
  }
}

// ---------------- K3a: per-chunk local inclusive scan (in place on Bu, fp32) ----------------
__global__ __launch_bounds__(256) void scan_local_k(float* __restrict__ Bu, const float2* __restrict__ dAf) {
  int unit = blockIdx.x * 4 + (threadIdx.x >> 6);   // b*NCH + c
  int p = threadIdx.x & 63;
  int b = unit >> 8, c = unit & 255;
  float2 dA = dAf[p];
  size_t base = ((size_t)b * LSEQ + (size_t)c * GCH) * 128;
  float hr = 0.f, hi = 0.f;
  for (int i0 = 0; i0 < GCH; i0 += 8) {
    float br[8], bi[8];
#pragma unroll
    for (int j = 0; j < 8; ++j) {
      br[j] = Bu[base + (size_t)(i0 + j) * 128 + p];
      bi[j] = Bu[base + (size_t)(i0 + j) * 128 + 64 + p];
    }
#pragma unroll
    for (int j = 0; j < 8; ++j) {
      float nr = fmaf(dA.x, hr, fmaf(-dA.y, hi, br[j]));
      float ni = fmaf(dA.x, hi, fmaf(dA.y, hr, bi[j]));
      hr = nr; hi = ni; br[j] = hr; bi[j] = hi;
    }
#pragma unroll
    for (int j = 0; j < 8; ++j) {
      Bu[base + (size_t)(i0 + j) * 128 + p] = br[j];
      Bu[base + (size_t)(i0 + j) * 128 + 64 + p] = bi[j];
    }
  }
}

// ---------------- K3b: chunk-carry prefix scan (batched prefetch) ----------------
__global__ void scan_carry_k(const float* __restrict__ Bu, float* __restrict__ offc,
                             const float2* __restrict__ powt) {
  int b = threadIdx.x >> 6;
  int p = threadIdx.x & 63;
  float2 dAG = powt[p * (GCH + 1) + GCH];   // dA^G
  float rr = 0.f, ri = 0.f;
  for (int c0 = 0; c0 < NCH; c0 += 8) {
    float er[8], ei[8];
#pragma unroll
    for (int j = 0; j < 8; ++j) {
      size_t n = (size_t)b * LSEQ + (size_t)(c0 + j) * GCH + (GCH - 1);
      er[j] = Bu[n * 128 + p];
      ei[j] = Bu[n * 128 + 64 + p];
    }
#pragma unroll
    for (int j = 0; j < 8; ++j) {
      size_t orow = (size_t)(b * NCH + c0 + j) * 128;
      offc[orow + p] = rr;
      offc[orow + 64 + p] = ri;
      float nr = fmaf(dAG.x, rr, fmaf(-dAG.y, ri, er[j]));
      float ni = fmaf(dAG.x, ri, fmaf(dAG.y, rr, ei[j]));
      rr = nr; ri = ni;
    }
  }
}

// ---------------- K3c: fixup h = local + dA^{i+1}*offset -> bf16 h ----------------
__global__ __launch_bounds__(256) void fixup_k(const float* __restrict__ Bu, const float* __restrict__ offc,
                                               const float2* __restrict__ powt, u16* __restrict__ hb) {
  size_t idx = (size_t)blockIdx.x * blockDim.x + threadIdx.x;
  const size_t total = (size_t)NTOK * 64;
  size_t stride = (size_t)gridDim.x * blockDim.x;
  for (; idx < total; idx += stride) {
    int p = (int)(idx & 63);
    size_t n = idx >> 6;
    int l = (int)(n & (LSEQ - 1));
    int i = l & (GCH - 1);
    float2 pw = powt[p * (GCH + 1) + i + 1];
    size_t crow = (n >> 6) * 128;
    float orr = offc[crow + p], oii = offc[crow + 64 + p];
    float hr = Bu[n * 128 + p]      + pw.x * orr - pw.y * oii;
    float hi = Bu[n * 128 + 64 + p] + pw.x * oii + pw.y * orr;
    hb[n * 128 + p] = f2bf(hr);
    hb[n * 128 + 64 + p] = f2bf(hi);
  }
}

extern "C" void kernel_launch(void* const* d_in, const int* in_sizes, int n_in,
                              void* d_out, int out_size, void* d_ws, size_t ws_size,
                              hipStream_t stream) {
  const float* x      = (const float*)d_in[0];
  const float* W_in   = (const float*)d_in[1];
  const float* W_out  = (const float*)d_in[2];
  const float* A_real = (const float*)d_in[3];
  const float* A_imag = (const float*)d_in[4];
  const float* B_re   = (const float*)d_in[5];
  const float* B_im   = (const float*)d_in[6];
  const float* C_re   = (const float*)d_in[7];
  const float* C_im   = (const float*)d_in[8];
  const float* Dv     = (const float*)d_in[9];
  const float* inv_dt = (const float*)d_in[10];

  // ---- workspace layout (bf16 buffers) ----
  u16* xb    = (u16*)d_ws;                       // N*256
  u16* u_bf  = xb + (size_t)NTOK * 256;          // N*512
  u16* sr_bf = u_bf + (size_t)NTOK * 512;        // N*512 (becomes g after K4a)
  u16* h_bf  = sr_bf + (size_t)NTOK * 512;       // N*128
  u16* WinT  = h_bf + (size_t)NTOK * 128;        // 1024*256
  u16* dBn   = WinT + 1024 * 256;                // 128*512
  u16* Ccb   = dBn + 128 * 512;                  // 512*128
  u16* WoutT = Ccb + 512 * 128;                  // 256*512

  // ---- d_out doubles as fp32 scratch (dead before final GEMM writes it) ----
  float* O    = (float*)d_out;
  float* Bu   = O;                        // N*128 = 8388608 floats
  float* offc = O + 8388608;              // 1024*128
  float2* powt = (float2*)(O + 8519680);  // 64*65 float2
  float2* dAf  = (float2*)(O + 8528000);  // 64 float2
  float2* fvec = (float2*)(O + 8528128);  // 64 float2

  setup_scalar_k<<<1, 64, 0, stream>>>(A_real, A_imag, inv_dt, dAf, fvec, powt);
  setup_tables_k<<<256, 256, 0, stream>>>(B_re, B_im, C_re, C_im, W_in, W_out, fvec,
                                          WinT, dBn, Ccb, WoutT);
  cvt_x_k<<<1024, 256, 0, stream>>>(x, xb);

  // K1: [u|res] = silu(x @ W_in)   (4096 blocks, 8 col tiles)
  mgemm<0, 3><<<4096, 256, 0, stream>>>(xb, WinT, u_bf, sr_bf, nullptr, 256);
  // K2: Bu = u @ dB^T (fp32 out)   (512 blocks, 1 col tile)
  mgemm<1, 0><<<512, 256, 0, stream>>>(u_bf, dBn, Bu, nullptr, nullptr, 512);
  // K3: chunked scan (fp32), emits bf16 h
  scan_local_k<<<256, 256, 0, stream>>>(Bu, dAf);
  scan_carry_k<<<1, 256, 0, stream>>>(Bu, offc, powt);
  fixup_k<<<4096, 256, 0, stream>>>(Bu, offc, powt, h_bf);
  // K4a: g = (Re(h C^T) + D*u) * sres  (2048 blocks, 4 col tiles)
  mgemm<2, 2><<<2048, 256, 0, stream>>>(h_bf, Ccb, u_bf, sr_bf, Dv, 128);
  // K4b: out = g @ W_out           (1024 blocks, 2 col tiles)
  mgemm<3, 1><<<1024, 256, 0, stream>>>(sr_bf, WoutT, O, nullptr, nullptr, 512);
}

// Round 4
// 253.938 us; speedup vs baseline: 3.5216x; 1.0260x over previous
//
#include <hip/hip_runtime.h>
#include <math.h>

#define NTOK 65536
#define LSEQ 16384
#define GCH 64
#define NCH 256   // LSEQ / GCH

typedef __attribute__((ext_vector_type(8))) short short8v;
typedef __attribute__((ext_vector_type(4))) float f32x4;
typedef unsigned short u16;

__device__ __forceinline__ u16 f2bf(float f) {
  unsigned u = __float_as_uint(f);
  return (u16)((u + 0x7FFFu + ((u >> 16) & 1u)) >> 16);
}
__device__ __forceinline__ float bf2f(u16 b) {
  return __uint_as_float(((unsigned)b) << 16);
}
__device__ __forceinline__ void gld16(const u16* g, u16* l) {
  __builtin_amdgcn_global_load_lds((const __attribute__((address_space(1))) void*)g,
                                   (__attribute__((address_space(3))) void*)l, 16, 0, 0);
}

// ---------------- K0a: scalar SSM parameter setup (fp64) ----------------
__global__ void setup_scalar_k(const float* __restrict__ A_real, const float* __restrict__ A_imag,
                               const float* __restrict__ inv_dt,
                               float2* __restrict__ dAf, float2* __restrict__ fvec,
                               float2* __restrict__ powt) {
  int p = threadIdx.x;
  if (p >= 64) return;
  double ar = (double)A_real[p], ai = (double)A_imag[p];
  double dt = log1p(exp((double)inv_dt[p]));   // softplus
  double zr = 0.5 * dt * ar, zi = 0.5 * dt * ai;
  double d1r = 1.0 - zr;
  double den = d1r * d1r + zi * zi;
  double blr = d1r / den, bli = zi / den;      // BL = 1/(1-z)
  double nr = 1.0 + zr, ni = zi;               // 1+z
  double dar = blr * nr - bli * ni;            // dA
  double dai = blr * ni + bli * nr;
  dAf[p] = make_float2((float)dar, (float)dai);
  fvec[p] = make_float2((float)(blr * dt), (float)(bli * dt));   // f = BL*dt
  double cr = 1.0, ci = 0.0;
  for (int k = 0; k <= GCH; ++k) {
    powt[p * (GCH + 1) + k] = make_float2((float)cr, (float)ci); // dA^k
    double t = cr * dar - ci * dai;
    ci = cr * dai + ci * dar;
    cr = t;
  }
}

// ---------------- K0b: build bf16 B^T-layout weight tables ----------------
__global__ void setup_tables_k(const float* __restrict__ B_re, const float* __restrict__ B_im,
                               const float* __restrict__ C_re, const float* __restrict__ C_im,
                               const float* __restrict__ W_in, const float* __restrict__ W_out,
                               const float2* __restrict__ fvec,
                               u16* __restrict__ WinT, u16* __restrict__ dBn,
                               u16* __restrict__ Ccb, u16* __restrict__ WoutT) {
  int idx = blockIdx.x * blockDim.x + threadIdx.x;
  int stride = gridDim.x * blockDim.x;
  // WinT [1024][256]
  for (int i = idx; i < 1024 * 256; i += stride) {
    int n = i >> 8, k = i & 255;
    WinT[i] = f2bf(W_in[k * 1024 + n]);
  }
  // dBn [128][512]  (rows 0-63 Re(dB), 64-127 Im(dB))
  for (int i = idx; i < 128 * 512; i += stride) {
    int p = i >> 9, d = i & 511;
    float2 f = fvec[p & 63];
    float br = B_re[(p & 63) * 512 + d], bi = B_im[(p & 63) * 512 + d];
    float v = (p < 64) ? (f.x * br - f.y * bi) : (f.x * bi + f.y * br);
    dBn[i] = f2bf(v);
  }
  // Ccb [512][128]  (cols 0-63: C_re, 64-127: -C_im)
  for (int i = idx; i < 512 * 128; i += stride) {
    int d = i >> 7, k = i & 127;
    float v = (k < 64) ? C_re[d * 64 + k] : -C_im[d * 64 + (k - 64)];
    Ccb[i] = f2bf(v);
  }
  // WoutT [256][512]
  for (int i = idx; i < 256 * 512; i += stride) {
    int n = i >> 9, k = i & 511;
    WoutT[i] = f2bf(W_out[k * 256 + n]);
  }
}

// ---------------- x -> bf16 ----------------
__global__ __launch_bounds__(256) void cvt_x_k(const float* __restrict__ x, u16* __restrict__ xb) {
  size_t i = ((size_t)blockIdx.x * blockDim.x + threadIdx.x) * 4;
  size_t stride = (size_t)gridDim.x * blockDim.x * 4;
  const size_t total = (size_t)NTOK * 256;
  for (; i < total; i += stride) {
    float4 v = *(const float4*)(x + i);
    ushort4 o;
    o.x = f2bf(v.x); o.y = f2bf(v.y); o.z = f2bf(v.z); o.w = f2bf(v.w);
    *(ushort4*)(xb + i) = o;
  }
}

// ---------------- bf16 MFMA GEMM: 128x128 tile, BK=32, 4 waves (2x2) ----------------
// 2-phase double-buffered K-loop (T3-minimum): STAGE(t+1) issued before
// ds_read+MFMA of t; one __syncthreads per step (its vmcnt/lgkm drain makes
// buffer reuse safe). LDS chunk swizzle: slot = chunk ^ ((row>>1)&3), applied
// on the global source (gld_lds dest is linear) and on the frag read -> 2-way
// bank access (free). Bijective XCD swizzle on a 1D grid.
// MODE 0: u/sres = silu(acc), split at col 512        (C0=u_bf, C1=sres_bf)
// MODE 1: C0(fp32)[m*128+n] = acc                     (Bu)
// MODE 2: g = (acc + D*u)*sres -> C1 (bf16, in place) (C0=u_bf, C1=sres_bf)
// MODE 3: C0(fp32)[m*256+n] = acc                     (final out)
template<int MODE, int LOG_NBX, int KDIM>
__global__ __launch_bounds__(256) void mgemm(
    const u16* __restrict__ A, const u16* __restrict__ Bt,
    void* __restrict__ C0, void* __restrict__ C1,
    const float* __restrict__ Dvec) {
  __shared__ u16 As[2][128 * 32];
  __shared__ u16 Bs[2][128 * 32];
  const int tid = threadIdx.x;
  const int w = tid >> 6, l = tid & 63;
  const int wm = w >> 1, wn = w & 1;

  // bijective XCD swizzle (gridDim.x % 8 == 0 for all launches)
  const int lin = blockIdx.x;
  const int cpx = gridDim.x >> 3;
  const int swz = (lin & 7) * cpx + (lin >> 3);
  const int n0 = (swz & ((1 << LOG_NBX) - 1)) * 128;
  const int m0 = (swz >> LOG_NBX) * 128;

  f32x4 acc[4][4] = {};

  const int lr = l >> 2;                       // staged row within 16-row chunk
  const int sc = (l & 3) ^ ((l >> 3) & 3);     // swizzled source chunk (row>>1 axis)
  const u16* gA = A + (size_t)(m0 + w * 32 + lr) * KDIM + sc * 8;
  const u16* gB = Bt + (size_t)(n0 + w * 32 + lr) * KDIM + sc * 8;
  const size_t rowskip = (size_t)16 * KDIM;

  const int fr = l & 15;
  const int kgs = (((l >> 4) ^ (l >> 1)) & 3) * 8;   // swizzled frag-read k-offset

  constexpr int NT = KDIM / 32;

  auto stage = [&](int buf, int k0) {
    u16* lA = &As[buf][w * 1024];
    u16* lB = &Bs[buf][w * 1024];
    gld16(gA + k0, lA);
    gld16(gA + k0 + rowskip, lA + 512);
    gld16(gB + k0, lB);
    gld16(gB + k0 + rowskip, lB + 512);
  };
  auto compute = [&](int buf) {
    short8v af[4], bfr[4];
#pragma unroll
    for (int mi = 0; mi < 4; ++mi)
      af[mi] = *(const short8v*)&As[buf][(wm * 64 + mi * 16 + fr) * 32 + kgs];
#pragma unroll
    for (int ni = 0; ni < 4; ++ni)
      bfr[ni] = *(const short8v*)&Bs[buf][(wn * 64 + ni * 16 + fr) * 32 + kgs];
#pragma unroll
    for (int mi = 0; mi < 4; ++mi)
#pragma unroll
      for (int ni = 0; ni < 4; ++ni)
        acc[mi][ni] = __builtin_amdgcn_mfma_f32_16x16x32_bf16(af[mi], bfr[ni], acc[mi][ni], 0, 0, 0);
  };

  stage(0, 0);
  __syncthreads();
#pragma unroll
  for (int t = 0; t < NT - 1; ++t) {
    stage((t + 1) & 1, (t + 1) * 32);   // prefetch next tile (in flight during MFMA)
    compute(t & 1);
    __syncthreads();                    // drains vmcnt (stage done) + lgkm (reads done)
  }
  compute((NT - 1) & 1);

  const int rbase = (l >> 4) * 4;
#pragma unroll
  for (int mi = 0; mi < 4; ++mi) {
#pragma unroll
    for (int ni = 0; ni < 4; ++ni) {
      int gr0 = m0 + wm * 64 + mi * 16 + rbase;
      int gc = n0 + wn * 64 + ni * 16 + fr;
#pragma unroll
      for (int j = 0; j < 4; ++j) {
        float v = acc[mi][ni][j];
        size_t r = (size_t)(gr0 + j);
        if (MODE == 0) {
          float s = v / (1.f + __expf(-v));
          if (gc < 512) ((u16*)C0)[r * 512 + gc] = f2bf(s);
          else          ((u16*)C1)[r * 512 + gc - 512] = f2bf(s);
        } else if (MODE == 1) {
          ((float*)C0)[r * 128 + gc] = v;
        } else if (MODE == 2) {
          float uu = bf2f(((const u16*)C0)[r * 512 + gc]);
          float sr = bf2f(((const u16*)C1)[r * 512 + gc]);
          float y = v + Dvec[gc] * uu;
          ((u16*)C1)[r * 512 + gc] = f2bf(y * sr);
        } else {
          ((float*)C0)[r * 256 + gc] = v;
        }
      }
    }
  }
}

// ---------------- K3a: per-chunk local inclusive scan (in place on Bu, fp32) ----------------
__global__ __launch_bounds__(256) void scan_local_k(float* __restrict__ Bu, const float2* __restrict__ dAf) {
  int unit = blockIdx.x * 4 + (threadIdx.x >> 6);   // b*NCH + c
  int p = threadIdx.x & 63;
  int b = unit >> 8, c = unit & 255;
  float2 dA = dAf[p];
  size_t base = ((size_t)b * LSEQ + (size_t)c * GCH) * 128;
  float hr = 0.f, hi = 0.f;
  for (int i0 = 0; i0 < GCH; i0 += 8) {
    float br[8], bi[8];
#pragma unroll
    for (int j = 0; j < 8; ++j) {
      br[j] = Bu[base + (size_t)(i0 + j) * 128 + p];
      bi[j] = Bu[base + (size_t)(i0 + j) * 128 + 64 + p];
    }
#pragma unroll
    for (int j = 0; j < 8; ++j) {
      float nr = fmaf(dA.x, hr, fmaf(-dA.y, hi, br[j]));
      float ni = fmaf(dA.x, hi, fmaf(dA.y, hr, bi[j]));
      hr = nr; hi = ni; br[j] = hr; bi[j] = hi;
    }
#pragma unroll
    for (int j = 0; j < 8; ++j) {
      Bu[base + (size_t)(i0 + j) * 128 + p] = br[j];
      Bu[base + (size_t)(i0 + j) * 128 + 64 + p] = bi[j];
    }
  }
}

// ---------------- K3b: chunk-carry prefix scan (batched prefetch) ----------------
__global__ void scan_carry_k(const float* __restrict__ Bu, float* __restrict__ offc,
                             const float2* __restrict__ powt) {
  int b = threadIdx.x >> 6;
  int p = threadIdx.x & 63;
  float2 dAG = powt[p * (GCH + 1) + GCH];   // dA^G
  float rr = 0.f, ri = 0.f;
  for (int c0 = 0; c0 < NCH; c0 += 8) {
    float er[8], ei[8];
#pragma unroll
    for (int j = 0; j < 8; ++j) {
      size_t n = (size_t)b * LSEQ + (size_t)(c0 + j) * GCH + (GCH - 1);
      er[j] = Bu[n * 128 + p];
      ei[j] = Bu[n * 128 + 64 + p];
    }
#pragma unroll
    for (int j = 0; j < 8; ++j) {
      size_t orow = (size_t)(b * NCH + c0 + j) * 128;
      offc[orow + p] = rr;
      offc[orow + 64 + p] = ri;
      float nr = fmaf(dAG.x, rr, fmaf(-dAG.y, ri, er[j]));
      float ni = fmaf(dAG.x, ri, fmaf(dAG.y, rr, ei[j]));
      rr = nr; ri = ni;
    }
  }
}

// ---------------- K3c: fixup h = local + dA^{i+1}*offset -> bf16 h ----------------
__global__ __launch_bounds__(256) void fixup_k(const float* __restrict__ Bu, const float* __restrict__ offc,
                                               const float2* __restrict__ powt, u16* __restrict__ hb) {
  size_t idx = (size_t)blockIdx.x * blockDim.x + threadIdx.x;
  const size_t total = (size_t)NTOK * 64;
  size_t stride = (size_t)gridDim.x * blockDim.x;
  for (; idx < total; idx += stride) {
    int p = (int)(idx & 63);
    size_t n = idx >> 6;
    int l = (int)(n & (LSEQ - 1));
    int i = l & (GCH - 1);
    float2 pw = powt[p * (GCH + 1) + i + 1];
    size_t crow = (n >> 6) * 128;
    float orr = offc[crow + p], oii = offc[crow + 64 + p];
    float hr = Bu[n * 128 + p]      + pw.x * orr - pw.y * oii;
    float hi = Bu[n * 128 + 64 + p] + pw.x * oii + pw.y * orr;
    hb[n * 128 + p] = f2bf(hr);
    hb[n * 128 + 64 + p] = f2bf(hi);
  }
}

extern "C" void kernel_launch(void* const* d_in, const int* in_sizes, int n_in,
                              void* d_out, int out_size, void* d_ws, size_t ws_size,
                              hipStream_t stream) {
  const float* x      = (const float*)d_in[0];
  const float* W_in   = (const float*)d_in[1];
  const float* W_out  = (const float*)d_in[2];
  const float* A_real = (const float*)d_in[3];
  const float* A_imag = (const float*)d_in[4];
  const float* B_re   = (const float*)d_in[5];
  const float* B_im   = (const float*)d_in[6];
  const float* C_re   = (const float*)d_in[7];
  const float* C_im   = (const float*)d_in[8];
  const float* Dv     = (const float*)d_in[9];
  const float* inv_dt = (const float*)d_in[10];

  // ---- workspace layout (bf16 buffers) ----
  u16* xb    = (u16*)d_ws;                       // N*256
  u16* u_bf  = xb + (size_t)NTOK * 256;          // N*512
  u16* sr_bf = u_bf + (size_t)NTOK * 512;        // N*512 (becomes g after K4a)
  u16* h_bf  = sr_bf + (size_t)NTOK * 512;       // N*128
  u16* WinT  = h_bf + (size_t)NTOK * 128;        // 1024*256
  u16* dBn   = WinT + 1024 * 256;                // 128*512
  u16* Ccb   = dBn + 128 * 512;                  // 512*128
  u16* WoutT = Ccb + 512 * 128;                  // 256*512

  // ---- d_out doubles as fp32 scratch (dead before final GEMM writes it) ----
  float* O    = (float*)d_out;
  float* Bu   = O;                        // N*128 = 8388608 floats
  float* offc = O + 8388608;              // 1024*128
  float2* powt = (float2*)(O + 8519680);  // 64*65 float2
  float2* dAf  = (float2*)(O + 8528000);  // 64 float2
  float2* fvec = (float2*)(O + 8528128);  // 64 float2

  setup_scalar_k<<<1, 64, 0, stream>>>(A_real, A_imag, inv_dt, dAf, fvec, powt);
  setup_tables_k<<<256, 256, 0, stream>>>(B_re, B_im, C_re, C_im, W_in, W_out, fvec,
                                          WinT, dBn, Ccb, WoutT);
  cvt_x_k<<<1024, 256, 0, stream>>>(x, xb);

  // K1: [u|res] = silu(x @ W_in)   (4096 blocks, 8 col tiles)
  mgemm<0, 3, 256><<<4096, 256, 0, stream>>>(xb, WinT, u_bf, sr_bf, nullptr);
  // K2: Bu = u @ dB^T (fp32 out)   (512 blocks, 1 col tile)
  mgemm<1, 0, 512><<<512, 256, 0, stream>>>(u_bf, dBn, Bu, nullptr, nullptr);
  // K3: chunked scan (fp32), emits bf16 h
  scan_local_k<<<256, 256, 0, stream>>>(Bu, dAf);
  scan_carry_k<<<1, 256, 0, stream>>>(Bu, offc, powt);
  fixup_k<<<4096, 256, 0, stream>>>(Bu, offc, powt, h_bf);
  // K4a: g = (Re(h C^T) + D*u) * sres  (2048 blocks, 4 col tiles)
  mgemm<2, 2, 128><<<2048, 256, 0, stream>>>(h_bf, Ccb, u_bf, sr_bf, Dv);
  // K4b: out = g @ W_out           (1024 blocks, 2 col tiles)
  mgemm<3, 1, 512><<<1024, 256, 0, stream>>>(sr_bf, WoutT, O, nullptr, nullptr);
}

// Round 5
// 237.279 us; speedup vs baseline: 3.7689x; 1.0702x over previous
//
#include <hip/hip_runtime.h>
#include <math.h>

#define NTOK 65536
#define LSEQ 16384
#define GCH 64
#define NCH 256   // LSEQ / GCH

typedef __attribute__((ext_vector_type(8))) short short8v;
typedef __attribute__((ext_vector_type(4))) float f32x4;
typedef unsigned short u16;

__device__ __forceinline__ u16 f2bf(float f) {
  unsigned u = __float_as_uint(f);
  return (u16)((u + 0x7FFFu + ((u >> 16) & 1u)) >> 16);
}
__device__ __forceinline__ float bf2f(u16 b) {
  return __uint_as_float(((unsigned)b) << 16);
}
__device__ __forceinline__ unsigned cvtpk_bf16(float lo, float hi) {
  unsigned r;
  asm("v_cvt_pk_bf16_f32 %0, %1, %2" : "=v"(r) : "v"(lo), "v"(hi));
  return r;
}
__device__ __forceinline__ float silu_f(float v) {
  return v * __builtin_amdgcn_rcpf(1.f + __expf(-v));
}
__device__ __forceinline__ void gld16(const u16* g, u16* l) {
  __builtin_amdgcn_global_load_lds((const __attribute__((address_space(1))) void*)g,
                                   (__attribute__((address_space(3))) void*)l, 16, 0, 0);
}

#define WAITV4 asm volatile("s_waitcnt vmcnt(4) lgkmcnt(0)" ::: "memory")
#define WAITV0 asm volatile("s_waitcnt vmcnt(0) lgkmcnt(0)" ::: "memory")
#define BARRAW asm volatile("s_barrier" ::: "memory")

// ---------------- K0a: scalar SSM parameter setup (fp64) ----------------
__global__ void setup_scalar_k(const float* __restrict__ A_real, const float* __restrict__ A_imag,
                               const float* __restrict__ inv_dt,
                               float2* __restrict__ dAf, float2* __restrict__ fvec,
                               float2* __restrict__ powt) {
  int p = threadIdx.x;
  if (p >= 64) return;
  double ar = (double)A_real[p], ai = (double)A_imag[p];
  double dt = log1p(exp((double)inv_dt[p]));   // softplus
  double zr = 0.5 * dt * ar, zi = 0.5 * dt * ai;
  double d1r = 1.0 - zr;
  double den = d1r * d1r + zi * zi;
  double blr = d1r / den, bli = zi / den;      // BL = 1/(1-z)
  double nr = 1.0 + zr, ni = zi;               // 1+z
  double dar = blr * nr - bli * ni;            // dA
  double dai = blr * ni + bli * nr;
  dAf[p] = make_float2((float)dar, (float)dai);
  fvec[p] = make_float2((float)(blr * dt), (float)(bli * dt));   // f = BL*dt
  double cr = 1.0, ci = 0.0;
  for (int k = 0; k <= GCH; ++k) {
    powt[p * (GCH + 1) + k] = make_float2((float)cr, (float)ci); // dA^k
    double t = cr * dar - ci * dai;
    ci = cr * dai + ci * dar;
    cr = t;
  }
}

// ---------------- K0b: build bf16 B^T-layout weight tables ----------------
__global__ void setup_tables_k(const float* __restrict__ B_re, const float* __restrict__ B_im,
                               const float* __restrict__ C_re, const float* __restrict__ C_im,
                               const float* __restrict__ W_in, const float* __restrict__ W_out,
                               const float2* __restrict__ fvec,
                               u16* __restrict__ WinT, u16* __restrict__ dBn,
                               u16* __restrict__ Ccb, u16* __restrict__ WoutT) {
  int idx = blockIdx.x * blockDim.x + threadIdx.x;
  int stride = gridDim.x * blockDim.x;
  // WinT [1024][256]
  for (int i = idx; i < 1024 * 256; i += stride) {
    int n = i >> 8, k = i & 255;
    WinT[i] = f2bf(W_in[k * 1024 + n]);
  }
  // dBn [128][512]  (rows 0-63 Re(dB), 64-127 Im(dB))
  for (int i = idx; i < 128 * 512; i += stride) {
    int p = i >> 9, d = i & 511;
    float2 f = fvec[p & 63];
    float br = B_re[(p & 63) * 512 + d], bi = B_im[(p & 63) * 512 + d];
    float v = (p < 64) ? (f.x * br - f.y * bi) : (f.x * bi + f.y * br);
    dBn[i] = f2bf(v);
  }
  // Ccb [512][128]  (cols 0-63: C_re, 64-127: -C_im)
  for (int i = idx; i < 512 * 128; i += stride) {
    int d = i >> 7, k = i & 127;
    float v = (k < 64) ? C_re[d * 64 + k] : -C_im[d * 64 + (k - 64)];
    Ccb[i] = f2bf(v);
  }
  // WoutT [256][512]
  for (int i = idx; i < 256 * 512; i += stride) {
    int n = i >> 9, k = i & 511;
    WoutT[i] = f2bf(W_out[k * 256 + n]);
  }
}

// ---------------- x -> bf16 ----------------
__global__ __launch_bounds__(256) void cvt_x_k(const float* __restrict__ x, u16* __restrict__ xb) {
  size_t i = ((size_t)blockIdx.x * blockDim.x + threadIdx.x) * 4;
  size_t stride = (size_t)gridDim.x * blockDim.x * 4;
  const size_t total = (size_t)NTOK * 256;
  for (; i < total; i += stride) {
    float4 v = *(const float4*)(x + i);
    ushort4 o;
    o.x = f2bf(v.x); o.y = f2bf(v.y); o.z = f2bf(v.z); o.w = f2bf(v.w);
    *(ushort4*)(xb + i) = o;
  }
}

// ---------------- bf16 MFMA GEMM: 128x128 tile, BK=32, 4 waves (2x2) ----------------
// Depth-2 prefetch pipeline (T3+T4 minimum): 3 LDS buffers; per step
// `s_waitcnt vmcnt(4) lgkmcnt(0)` + raw s_barrier, so stage(t+1)'s 4 loads
// stay in flight across the barrier. lgkmcnt(0) before the barrier makes
// buf((t+2)%3) safe to overwrite (all waves' ds_reads of it completed).
// LDS chunk swizzle: slot = chunk ^ ((row>>1)&3) applied source-side and on
// the frag read -> 2-way bank access (free). Bijective XCD swizzle, 1D grid.
// MODE 0: u/sres = silu(acc), split at col 512        (C0=u_bf, C1=sres_bf)
// MODE 1: C0(fp32)[m*128+n] = acc                     (Bu)
// MODE 2: g = (acc + D*u)*sres -> C1 (bf16, in place) (C0=u_bf, C1=sres_bf)
// MODE 3: C0(fp32)[m*256+n] = acc                     (final out)
template<int MODE, int LOG_NBX, int KDIM>
__global__ __launch_bounds__(256) void mgemm(
    const u16* __restrict__ A, const u16* __restrict__ Bt,
    void* __restrict__ C0, void* __restrict__ C1,
    const float* __restrict__ Dvec) {
  __shared__ u16 As[3][128 * 32];
  __shared__ u16 Bs[3][128 * 32];
  const int tid = threadIdx.x;
  const int w = tid >> 6, l = tid & 63;
  const int wm = w >> 1, wn = w & 1;

  // bijective XCD swizzle (gridDim.x % 8 == 0 for all launches)
  const int lin = blockIdx.x;
  const int cpx = gridDim.x >> 3;
  const int swz = (lin & 7) * cpx + (lin >> 3);
  const int n0 = (swz & ((1 << LOG_NBX) - 1)) * 128;
  const int m0 = (swz >> LOG_NBX) * 128;

  f32x4 acc[4][4] = {};

  const int lr = l >> 2;                       // staged row within 16-row chunk
  const int sc = (l & 3) ^ ((l >> 3) & 3);     // swizzled source chunk
  const u16* gA = A + (size_t)(m0 + w * 32 + lr) * KDIM + sc * 8;
  const u16* gB = Bt + (size_t)(n0 + w * 32 + lr) * KDIM + sc * 8;
  const size_t rowskip = (size_t)16 * KDIM;

  const int fr = l & 15;
  const int kgs = (((l >> 4) ^ (l >> 1)) & 3) * 8;   // swizzled frag-read k-offset

  constexpr int NT = KDIM / 32;

  auto stage = [&](int buf, int k0) {
    u16* lA = &As[buf][w * 1024];
    u16* lB = &Bs[buf][w * 1024];
    gld16(gA + k0, lA);
    gld16(gA + k0 + rowskip, lA + 512);
    gld16(gB + k0, lB);
    gld16(gB + k0 + rowskip, lB + 512);
  };
  auto compute = [&](int buf) {
    short8v af[4], bfr[4];
#pragma unroll
    for (int mi = 0; mi < 4; ++mi)
      af[mi] = *(const short8v*)&As[buf][(wm * 64 + mi * 16 + fr) * 32 + kgs];
#pragma unroll
    for (int ni = 0; ni < 4; ++ni)
      bfr[ni] = *(const short8v*)&Bs[buf][(wn * 64 + ni * 16 + fr) * 32 + kgs];
#pragma unroll
    for (int mi = 0; mi < 4; ++mi)
#pragma unroll
      for (int ni = 0; ni < 4; ++ni)
        acc[mi][ni] = __builtin_amdgcn_mfma_f32_16x16x32_bf16(af[mi], bfr[ni], acc[mi][ni], 0, 0, 0);
  };

  stage(0, 0);
  if (NT > 1) stage(1, 32);
#pragma unroll
  for (int t = 0; t < NT; ++t) {
    if (t + 1 < NT) { WAITV4; } else { WAITV0; }
    BARRAW;
    if (t + 2 < NT) stage((t + 2) % 3, (t + 2) * 32);
    compute(t % 3);
  }

  const int rbase = (l >> 4) * 4;
#pragma unroll
  for (int mi = 0; mi < 4; ++mi) {
#pragma unroll
    for (int ni = 0; ni < 4; ++ni) {
      int gr0 = m0 + wm * 64 + mi * 16 + rbase;
      int gc = n0 + wn * 64 + ni * 16 + fr;
      if (MODE == 0) {
        float s0 = silu_f(acc[mi][ni][0]);
        float s1 = silu_f(acc[mi][ni][1]);
        float s2 = silu_f(acc[mi][ni][2]);
        float s3 = silu_f(acc[mi][ni][3]);
        unsigned p01 = cvtpk_bf16(s0, s1);
        unsigned p23 = cvtpk_bf16(s2, s3);
        u16* Cw = (n0 < 512) ? (u16*)C0 : (u16*)C1;
        int col = gc - ((n0 < 512) ? 0 : 512);
        Cw[(size_t)(gr0 + 0) * 512 + col] = (u16)p01;
        Cw[(size_t)(gr0 + 1) * 512 + col] = (u16)(p01 >> 16);
        Cw[(size_t)(gr0 + 2) * 512 + col] = (u16)p23;
        Cw[(size_t)(gr0 + 3) * 512 + col] = (u16)(p23 >> 16);
      } else if (MODE == 1) {
#pragma unroll
        for (int j = 0; j < 4; ++j)
          ((float*)C0)[(size_t)(gr0 + j) * 128 + gc] = acc[mi][ni][j];
      } else if (MODE == 2) {
        float g[4];
#pragma unroll
        for (int j = 0; j < 4; ++j) {
          size_t r = (size_t)(gr0 + j);
          float uu = bf2f(((const u16*)C0)[r * 512 + gc]);
          float sr = bf2f(((const u16*)C1)[r * 512 + gc]);
          g[j] = (acc[mi][ni][j] + Dvec[gc] * uu) * sr;
        }
        unsigned p01 = cvtpk_bf16(g[0], g[1]);
        unsigned p23 = cvtpk_bf16(g[2], g[3]);
        ((u16*)C1)[(size_t)(gr0 + 0) * 512 + gc] = (u16)p01;
        ((u16*)C1)[(size_t)(gr0 + 1) * 512 + gc] = (u16)(p01 >> 16);
        ((u16*)C1)[(size_t)(gr0 + 2) * 512 + gc] = (u16)p23;
        ((u16*)C1)[(size_t)(gr0 + 3) * 512 + gc] = (u16)(p23 >> 16);
      } else {
#pragma unroll
        for (int j = 0; j < 4; ++j)
          ((float*)C0)[(size_t)(gr0 + j) * 256 + gc] = acc[mi][ni][j];
      }
    }
  }
}

// ---------------- K3a: per-chunk local inclusive scan (in place on Bu, fp32) ----------------
__global__ __launch_bounds__(256) void scan_local_k(float* __restrict__ Bu, const float2* __restrict__ dAf) {
  int unit = blockIdx.x * 4 + (threadIdx.x >> 6);   // b*NCH + c
  int p = threadIdx.x & 63;
  int b = unit >> 8, c = unit & 255;
  float2 dA = dAf[p];
  size_t base = ((size_t)b * LSEQ + (size_t)c * GCH) * 128;
  float hr = 0.f, hi = 0.f;
  for (int i0 = 0; i0 < GCH; i0 += 8) {
    float br[8], bi[8];
#pragma unroll
    for (int j = 0; j < 8; ++j) {
      br[j] = Bu[base + (size_t)(i0 + j) * 128 + p];
      bi[j] = Bu[base + (size_t)(i0 + j) * 128 + 64 + p];
    }
#pragma unroll
    for (int j = 0; j < 8; ++j) {
      float nr = fmaf(dA.x, hr, fmaf(-dA.y, hi, br[j]));
      float ni = fmaf(dA.x, hi, fmaf(dA.y, hr, bi[j]));
      hr = nr; hi = ni; br[j] = hr; bi[j] = hi;
    }
#pragma unroll
    for (int j = 0; j < 8; ++j) {
      Bu[base + (size_t)(i0 + j) * 128 + p] = br[j];
      Bu[base + (size_t)(i0 + j) * 128 + 64 + p] = bi[j];
    }
  }
}

// ---------------- K3b: chunk-carry prefix scan (batched prefetch) ----------------
__global__ void scan_carry_k(const float* __restrict__ Bu, float* __restrict__ offc,
                             const float2* __restrict__ powt) {
  int b = threadIdx.x >> 6;
  int p = threadIdx.x & 63;
  float2 dAG = powt[p * (GCH + 1) + GCH];   // dA^G
  float rr = 0.f, ri = 0.f;
  for (int c0 = 0; c0 < NCH; c0 += 8) {
    float er[8], ei[8];
#pragma unroll
    for (int j = 0; j < 8; ++j) {
      size_t n = (size_t)b * LSEQ + (size_t)(c0 + j) * GCH + (GCH - 1);
      er[j] = Bu[n * 128 + p];
      ei[j] = Bu[n * 128 + 64 + p];
    }
#pragma unroll
    for (int j = 0; j < 8; ++j) {
      size_t orow = (size_t)(b * NCH + c0 + j) * 128;
      offc[orow + p] = rr;
      offc[orow + 64 + p] = ri;
      float nr = fmaf(dAG.x, rr, fmaf(-dAG.y, ri, er[j]));
      float ni = fmaf(dAG.x, ri, fmaf(dAG.y, rr, ei[j]));
      rr = nr; ri = ni;
    }
  }
}

// ---------------- K3c: fixup h = local + dA^{i+1}*offset -> bf16 h ----------------
__global__ __launch_bounds__(256) void fixup_k(const float* __restrict__ Bu, const float* __restrict__ offc,
                                               const float2* __restrict__ powt, u16* __restrict__ hb) {
  size_t idx = (size_t)blockIdx.x * blockDim.x + threadIdx.x;
  const size_t total = (size_t)NTOK * 64;
  size_t stride = (size_t)gridDim.x * blockDim.x;
  for (; idx < total; idx += stride) {
    int p = (int)(idx & 63);
    size_t n = idx >> 6;
    int l = (int)(n & (LSEQ - 1));
    int i = l & (GCH - 1);
    float2 pw = powt[p * (GCH + 1) + i + 1];
    size_t crow = (n >> 6) * 128;
    float orr = offc[crow + p], oii = offc[crow + 64 + p];
    float hr = Bu[n * 128 + p]      + pw.x * orr - pw.y * oii;
    float hi = Bu[n * 128 + 64 + p] + pw.x * oii + pw.y * orr;
    hb[n * 128 + p] = f2bf(hr);
    hb[n * 128 + 64 + p] = f2bf(hi);
  }
}

extern "C" void kernel_launch(void* const* d_in, const int* in_sizes, int n_in,
                              void* d_out, int out_size, void* d_ws, size_t ws_size,
                              hipStream_t stream) {
  const float* x      = (const float*)d_in[0];
  const float* W_in   = (const float*)d_in[1];
  const float* W_out  = (const float*)d_in[2];
  const float* A_real = (const float*)d_in[3];
  const float* A_imag = (const float*)d_in[4];
  const float* B_re   = (const float*)d_in[5];
  const float* B_im   = (const float*)d_in[6];
  const float* C_re   = (const float*)d_in[7];
  const float* C_im   = (const float*)d_in[8];
  const float* Dv     = (const float*)d_in[9];
  const float* inv_dt = (const float*)d_in[10];

  // ---- workspace layout (bf16 buffers) ----
  u16* xb    = (u16*)d_ws;                       // N*256
  u16* u_bf  = xb + (size_t)NTOK * 256;          // N*512
  u16* sr_bf = u_bf + (size_t)NTOK * 512;        // N*512 (becomes g after K4a)
  u16* h_bf  = sr_bf + (size_t)NTOK * 512;       // N*128
  u16* WinT  = h_bf + (size_t)NTOK * 128;        // 1024*256
  u16* dBn   = WinT + 1024 * 256;                // 128*512
  u16* Ccb   = dBn + 128 * 512;                  // 512*128
  u16* WoutT = Ccb + 512 * 128;                  // 256*512

  // ---- d_out doubles as fp32 scratch (dead before final GEMM writes it) ----
  float* O    = (float*)d_out;
  float* Bu   = O;                        // N*128 = 8388608 floats
  float* offc = O + 8388608;              // 1024*128
  float2* powt = (float2*)(O + 8519680);  // 64*65 float2
  float2* dAf  = (float2*)(O + 8528000);  // 64 float2
  float2* fvec = (float2*)(O + 8528128);  // 64 float2

  setup_scalar_k<<<1, 64, 0, stream>>>(A_real, A_imag, inv_dt, dAf, fvec, powt);
  setup_tables_k<<<256, 256, 0, stream>>>(B_re, B_im, C_re, C_im, W_in, W_out, fvec,
                                          WinT, dBn, Ccb, WoutT);
  cvt_x_k<<<1024, 256, 0, stream>>>(x, xb);

  // K1: [u|res] = silu(x @ W_in)   (4096 blocks, 8 col tiles)
  mgemm<0, 3, 256><<<4096, 256, 0, stream>>>(xb, WinT, u_bf, sr_bf, nullptr);
  // K2: Bu = u @ dB^T (fp32 out)   (512 blocks, 1 col tile)
  mgemm<1, 0, 512><<<512, 256, 0, stream>>>(u_bf, dBn, Bu, nullptr, nullptr);
  // K3: chunked scan (fp32), emits bf16 h
  scan_local_k<<<256, 256, 0, stream>>>(Bu, dAf);
  scan_carry_k<<<1, 256, 0, stream>>>(Bu, offc, powt);
  fixup_k<<<4096, 256, 0, stream>>>(Bu, offc, powt, h_bf);
  // K4a: g = (Re(h C^T) + D*u) * sres  (2048 blocks, 4 col tiles)
  mgemm<2, 2, 128><<<2048, 256, 0, stream>>>(h_bf, Ccb, u_bf, sr_bf, Dv);
  // K4b: out = g @ W_out           (1024 blocks, 2 col tiles)
  mgemm<3, 1, 512><<<1024, 256, 0, stream>>>(sr_bf, WoutT, O, nullptr, nullptr);
}

// Round 6
// 210.217 us; speedup vs baseline: 4.2541x; 1.1287x over previous
//
#include <hip/hip_runtime.h>
#include <math.h>

#define NTOK 65536
#define LSEQ 16384
#define GCH 64
#define NCH 256   // LSEQ / GCH

typedef __attribute__((ext_vector_type(8))) short short8v;
typedef __attribute__((ext_vector_type(4))) float f32x4;
typedef unsigned short u16;

__device__ __forceinline__ u16 f2bf(float f) {
  unsigned u = __float_as_uint(f);
  return (u16)((u + 0x7FFFu + ((u >> 16) & 1u)) >> 16);
}
__device__ __forceinline__ float bf2f(u16 b) {
  return __uint_as_float(((unsigned)b) << 16);
}
__device__ __forceinline__ unsigned cvtpk_bf16(float lo, float hi) {
  unsigned r;
  asm("v_cvt_pk_bf16_f32 %0, %1, %2" : "=v"(r) : "v"(lo), "v"(hi));
  return r;
}
__device__ __forceinline__ float silu_f(float v) {
  return v * __builtin_amdgcn_rcpf(1.f + __expf(-v));
}
__device__ __forceinline__ void gld16(const u16* g, u16* l) {
  __builtin_amdgcn_global_load_lds((const __attribute__((address_space(1))) void*)g,
                                   (__attribute__((address_space(3))) void*)l, 16, 0, 0);
}

#define WAITV2 asm volatile("s_waitcnt vmcnt(2) lgkmcnt(0)" ::: "memory")
#define WAITV0 asm volatile("s_waitcnt vmcnt(0) lgkmcnt(0)" ::: "memory")
#define BARRAW asm volatile("s_barrier" ::: "memory")

// ---------------- K0a: scalar SSM parameter setup (fp64) ----------------
__global__ void setup_scalar_k(const float* __restrict__ A_real, const float* __restrict__ A_imag,
                               const float* __restrict__ inv_dt,
                               float2* __restrict__ dAf, float2* __restrict__ fvec,
                               float2* __restrict__ powt) {
  int p = threadIdx.x;
  if (p >= 64) return;
  double ar = (double)A_real[p], ai = (double)A_imag[p];
  double dt = log1p(exp((double)inv_dt[p]));   // softplus
  double zr = 0.5 * dt * ar, zi = 0.5 * dt * ai;
  double d1r = 1.0 - zr;
  double den = d1r * d1r + zi * zi;
  double blr = d1r / den, bli = zi / den;      // BL = 1/(1-z)
  double nr = 1.0 + zr, ni = zi;               // 1+z
  double dar = blr * nr - bli * ni;            // dA
  double dai = blr * ni + bli * nr;
  dAf[p] = make_float2((float)dar, (float)dai);
  fvec[p] = make_float2((float)(blr * dt), (float)(bli * dt));   // f = BL*dt
  double cr = 1.0, ci = 0.0;
  for (int k = 0; k <= GCH; ++k) {
    powt[p * (GCH + 1) + k] = make_float2((float)cr, (float)ci); // dA^k
    double t = cr * dar - ci * dai;
    ci = cr * dai + ci * dar;
    cr = t;
  }
}

// ---------------- K0b: build bf16 B^T-layout weight tables ----------------
__global__ void setup_tables_k(const float* __restrict__ B_re, const float* __restrict__ B_im,
                               const float* __restrict__ C_re, const float* __restrict__ C_im,
                               const float* __restrict__ W_in, const float* __restrict__ W_out,
                               const float2* __restrict__ fvec,
                               u16* __restrict__ WinT, u16* __restrict__ dBn,
                               u16* __restrict__ Ccb, u16* __restrict__ WoutT) {
  int idx = blockIdx.x * blockDim.x + threadIdx.x;
  int stride = gridDim.x * blockDim.x;
  // WinT [1024][256]
  for (int i = idx; i < 1024 * 256; i += stride) {
    int n = i >> 8, k = i & 255;
    WinT[i] = f2bf(W_in[k * 1024 + n]);
  }
  // dBn [128][512]  (rows 0-63 Re(dB), 64-127 Im(dB))
  for (int i = idx; i < 128 * 512; i += stride) {
    int p = i >> 9, d = i & 511;
    float2 f = fvec[p & 63];
    float br = B_re[(p & 63) * 512 + d], bi = B_im[(p & 63) * 512 + d];
    float v = (p < 64) ? (f.x * br - f.y * bi) : (f.x * bi + f.y * br);
    dBn[i] = f2bf(v);
  }
  // Ccb [512][128]  (cols 0-63: C_re, 64-127: -C_im)
  for (int i = idx; i < 512 * 128; i += stride) {
    int d = i >> 7, k = i & 127;
    float v = (k < 64) ? C_re[d * 64 + k] : -C_im[d * 64 + (k - 64)];
    Ccb[i] = f2bf(v);
  }
  // WoutT [256][512]
  for (int i = idx; i < 256 * 512; i += stride) {
    int n = i >> 9, k = i & 511;
    WoutT[i] = f2bf(W_out[k * 256 + n]);
  }
}

// ---------------- x -> bf16 ----------------
__global__ __launch_bounds__(256) void cvt_x_k(const float* __restrict__ x, u16* __restrict__ xb) {
  size_t i = ((size_t)blockIdx.x * blockDim.x + threadIdx.x) * 4;
  size_t stride = (size_t)gridDim.x * blockDim.x * 4;
  const size_t total = (size_t)NTOK * 256;
  for (; i < total; i += stride) {
    float4 v = *(const float4*)(x + i);
    ushort4 o;
    o.x = f2bf(v.x); o.y = f2bf(v.y); o.z = f2bf(v.z); o.w = f2bf(v.w);
    *(ushort4*)(xb + i) = o;
  }
}

// ---------------- bf16 MFMA GEMM: 128x128 tile, BK=32, 8 waves (2x4), 512 thr ----
// Depth-2 prefetch (3 LDS bufs); per step `s_waitcnt vmcnt(2) lgkmcnt(0)` +
// raw s_barrier keeps stage(t+1)'s 2 loads (1 A + 1 B per thread) in flight
// across the barrier. 8 waves/block halves per-thread work and doubles
// waves-per-LDS-byte vs 4-wave version (occupancy was the R5 limiter).
// LDS chunk swizzle: slot = chunk ^ ((row>>1)&3), source-side + frag-read.
// Bijective XCD swizzle on 1D grid.
// MODE 0: u/sres = silu(acc), split at col 512        (C0=u_bf, C1=sres_bf)
// MODE 1: C0(fp32)[m*128+n] = acc                     (Bu)
// MODE 2: g = (acc + D*u)*sres -> C1 (bf16, in place) (C0=u_bf, C1=sres_bf)
// MODE 3: C0(fp32)[m*256+n] = acc                     (final out)
template<int MODE, int LOG_NBX, int KDIM>
__global__ __launch_bounds__(512) void mgemm(
    const u16* __restrict__ A, const u16* __restrict__ Bt,
    void* __restrict__ C0, void* __restrict__ C1,
    const float* __restrict__ Dvec) {
  __shared__ u16 As[3][128 * 32];
  __shared__ u16 Bs[3][128 * 32];
  const int tid = threadIdx.x;
  const int w = tid >> 6, l = tid & 63;
  const int wm = w >> 2, wn = w & 3;   // 2 x 4 wave grid; wave tile 64x32

  // bijective XCD swizzle (gridDim.x % 8 == 0 for all launches)
  const int lin = blockIdx.x;
  const int cpx = gridDim.x >> 3;
  const int swz = (lin & 7) * cpx + (lin >> 3);
  const int n0 = (swz & ((1 << LOG_NBX) - 1)) * 128;
  const int m0 = (swz >> LOG_NBX) * 128;

  f32x4 acc[4][2] = {};

  const int lr = l >> 2;                       // staged row within 16-row chunk
  const int sc = (l & 3) ^ ((l >> 3) & 3);     // swizzled source chunk
  const u16* gA = A + (size_t)(m0 + w * 16 + lr) * KDIM + sc * 8;
  const u16* gB = Bt + (size_t)(n0 + w * 16 + lr) * KDIM + sc * 8;

  const int fr = l & 15;
  const int kgs = (((l >> 4) ^ (l >> 1)) & 3) * 8;   // swizzled frag-read k-offset

  constexpr int NT = KDIM / 32;

  auto stage = [&](int buf, int k0) {
    gld16(gA + k0, &As[buf][w * 512]);
    gld16(gB + k0, &Bs[buf][w * 512]);
  };
  auto compute = [&](int buf) {
    short8v af[4], bfr[2];
#pragma unroll
    for (int mi = 0; mi < 4; ++mi)
      af[mi] = *(const short8v*)&As[buf][(wm * 64 + mi * 16 + fr) * 32 + kgs];
#pragma unroll
    for (int ni = 0; ni < 2; ++ni)
      bfr[ni] = *(const short8v*)&Bs[buf][(wn * 32 + ni * 16 + fr) * 32 + kgs];
#pragma unroll
    for (int mi = 0; mi < 4; ++mi)
#pragma unroll
      for (int ni = 0; ni < 2; ++ni)
        acc[mi][ni] = __builtin_amdgcn_mfma_f32_16x16x32_bf16(af[mi], bfr[ni], acc[mi][ni], 0, 0, 0);
  };

  stage(0, 0);
  if (NT > 1) stage(1, 32);
#pragma unroll
  for (int t = 0; t < NT; ++t) {
    if (t + 1 < NT) { WAITV2; } else { WAITV0; }
    BARRAW;
    if (t + 2 < NT) stage((t + 2) % 3, (t + 2) * 32);
    compute(t % 3);
  }

  const int rbase = (l >> 4) * 4;
#pragma unroll
  for (int mi = 0; mi < 4; ++mi) {
#pragma unroll
    for (int ni = 0; ni < 2; ++ni) {
      int gr0 = m0 + wm * 64 + mi * 16 + rbase;
      int gc = n0 + wn * 32 + ni * 16 + fr;
      if (MODE == 0) {
        float s0 = silu_f(acc[mi][ni][0]);
        float s1 = silu_f(acc[mi][ni][1]);
        float s2 = silu_f(acc[mi][ni][2]);
        float s3 = silu_f(acc[mi][ni][3]);
        unsigned p01 = cvtpk_bf16(s0, s1);
        unsigned p23 = cvtpk_bf16(s2, s3);
        u16* Cw = (n0 < 512) ? (u16*)C0 : (u16*)C1;
        int col = gc - ((n0 < 512) ? 0 : 512);
        Cw[(size_t)(gr0 + 0) * 512 + col] = (u16)p01;
        Cw[(size_t)(gr0 + 1) * 512 + col] = (u16)(p01 >> 16);
        Cw[(size_t)(gr0 + 2) * 512 + col] = (u16)p23;
        Cw[(size_t)(gr0 + 3) * 512 + col] = (u16)(p23 >> 16);
      } else if (MODE == 1) {
#pragma unroll
        for (int j = 0; j < 4; ++j)
          ((float*)C0)[(size_t)(gr0 + j) * 128 + gc] = acc[mi][ni][j];
      } else if (MODE == 2) {
        float g[4];
#pragma unroll
        for (int j = 0; j < 4; ++j) {
          size_t r = (size_t)(gr0 + j);
          float uu = bf2f(((const u16*)C0)[r * 512 + gc]);
          float sr = bf2f(((const u16*)C1)[r * 512 + gc]);
          g[j] = (acc[mi][ni][j] + Dvec[gc] * uu) * sr;
        }
        unsigned p01 = cvtpk_bf16(g[0], g[1]);
        unsigned p23 = cvtpk_bf16(g[2], g[3]);
        ((u16*)C1)[(size_t)(gr0 + 0) * 512 + gc] = (u16)p01;
        ((u16*)C1)[(size_t)(gr0 + 1) * 512 + gc] = (u16)(p01 >> 16);
        ((u16*)C1)[(size_t)(gr0 + 2) * 512 + gc] = (u16)p23;
        ((u16*)C1)[(size_t)(gr0 + 3) * 512 + gc] = (u16)(p23 >> 16);
      } else {
#pragma unroll
        for (int j = 0; j < 4; ++j)
          ((float*)C0)[(size_t)(gr0 + j) * 256 + gc] = acc[mi][ni][j];
      }
    }
  }
}

// ---------------- K3a: per-chunk carry sum (read-only over Bu) ----------------
// carr[unit] = sum_i dA^{G-1-i} Bu_i  == last element of the local scan.
__global__ __launch_bounds__(256) void scan_sum_k(const float* __restrict__ Bu,
                                                  float* __restrict__ carr,
                                                  const float2* __restrict__ dAf) {
  int unit = blockIdx.x * 4 + (threadIdx.x >> 6);   // b*NCH + c
  int p = threadIdx.x & 63;
  int b = unit >> 8, c = unit & 255;
  float2 dA = dAf[p];
  size_t base = ((size_t)b * LSEQ + (size_t)c * GCH) * 128;
  float rr = 0.f, ri = 0.f;
  for (int i0 = 0; i0 < GCH; i0 += 8) {
    float br[8], bi[8];
#pragma unroll
    for (int j = 0; j < 8; ++j) {
      br[j] = Bu[base + (size_t)(i0 + j) * 128 + p];
      bi[j] = Bu[base + (size_t)(i0 + j) * 128 + 64 + p];
    }
#pragma unroll
    for (int j = 0; j < 8; ++j) {
      float nr = fmaf(dA.x, rr, fmaf(-dA.y, ri, br[j]));
      float ni = fmaf(dA.x, ri, fmaf(dA.y, rr, bi[j]));
      rr = nr; ri = ni;
    }
  }
  carr[(size_t)unit * 128 + p] = rr;
  carr[(size_t)unit * 128 + 64 + p] = ri;
}

// ---------------- K3b: chunk-carry exclusive prefix scan ----------------
__global__ void scan_carry_k(const float* __restrict__ carr, float* __restrict__ offc,
                             const float2* __restrict__ powt) {
  int b = threadIdx.x >> 6;
  int p = threadIdx.x & 63;
  float2 dAG = powt[p * (GCH + 1) + GCH];   // dA^G
  float rr = 0.f, ri = 0.f;
  for (int c0 = 0; c0 < NCH; c0 += 8) {
    float er[8], ei[8];
#pragma unroll
    for (int j = 0; j < 8; ++j) {
      size_t crow = (size_t)(b * NCH + c0 + j) * 128;
      er[j] = carr[crow + p];
      ei[j] = carr[crow + 64 + p];
    }
#pragma unroll
    for (int j = 0; j < 8; ++j) {
      size_t orow = (size_t)(b * NCH + c0 + j) * 128;
      offc[orow + p] = rr;
      offc[orow + 64 + p] = ri;
      float nr = fmaf(dAG.x, rr, fmaf(-dAG.y, ri, er[j]));
      float ni = fmaf(dAG.x, ri, fmaf(dAG.y, rr, ei[j]));
      rr = nr; ri = ni;
    }
  }
}

// ---------------- K3c: seeded local scan, emits bf16 h directly ----------------
// h_t = dA*h_{t-1} + Bu_t with h_{-1} = offc  ==  local + dA^{i+1}*offset.
__global__ __launch_bounds__(256) void scan_emit_k(const float* __restrict__ Bu,
                                                   const float* __restrict__ offc,
                                                   u16* __restrict__ hb,
                                                   const float2* __restrict__ dAf) {
  int unit = blockIdx.x * 4 + (threadIdx.x >> 6);   // b*NCH + c
  int p = threadIdx.x & 63;
  int b = unit >> 8, c = unit & 255;
  float2 dA = dAf[p];
  size_t base = ((size_t)b * LSEQ + (size_t)c * GCH) * 128;
  float hr = offc[(size_t)unit * 128 + p];
  float hi = offc[(size_t)unit * 128 + 64 + p];
  for (int i0 = 0; i0 < GCH; i0 += 8) {
    float br[8], bi[8];
#pragma unroll
    for (int j = 0; j < 8; ++j) {
      br[j] = Bu[base + (size_t)(i0 + j) * 128 + p];
      bi[j] = Bu[base + (size_t)(i0 + j) * 128 + 64 + p];
    }
#pragma unroll
    for (int j = 0; j < 8; ++j) {
      float nr = fmaf(dA.x, hr, fmaf(-dA.y, hi, br[j]));
      float ni = fmaf(dA.x, hi, fmaf(dA.y, hr, bi[j]));
      hr = nr; hi = ni;
      hb[base + (size_t)(i0 + j) * 128 + p] = f2bf(hr);
      hb[base + (size_t)(i0 + j) * 128 + 64 + p] = f2bf(hi);
    }
  }
}

extern "C" void kernel_launch(void* const* d_in, const int* in_sizes, int n_in,
                              void* d_out, int out_size, void* d_ws, size_t ws_size,
                              hipStream_t stream) {
  const float* x      = (const float*)d_in[0];
  const float* W_in   = (const float*)d_in[1];
  const float* W_out  = (const float*)d_in[2];
  const float* A_real = (const float*)d_in[3];
  const float* A_imag = (const float*)d_in[4];
  const float* B_re   = (const float*)d_in[5];
  const float* B_im   = (const float*)d_in[6];
  const float* C_re   = (const float*)d_in[7];
  const float* C_im   = (const float*)d_in[8];
  const float* Dv     = (const float*)d_in[9];
  const float* inv_dt = (const float*)d_in[10];

  // ---- workspace layout (bf16 buffers) ----
  u16* xb    = (u16*)d_ws;                       // N*256
  u16* u_bf  = xb + (size_t)NTOK * 256;          // N*512
  u16* sr_bf = u_bf + (size_t)NTOK * 512;        // N*512 (becomes g after K4a)
  u16* h_bf  = sr_bf + (size_t)NTOK * 512;       // N*128
  u16* WinT  = h_bf + (size_t)NTOK * 128;        // 1024*256
  u16* dBn   = WinT + 1024 * 256;                // 128*512
  u16* Ccb   = dBn + 128 * 512;                  // 512*128
  u16* WoutT = Ccb + 512 * 128;                  // 256*512

  // ---- d_out doubles as fp32 scratch (dead before final GEMM writes it) ----
  float* O    = (float*)d_out;
  float* Bu   = O;                        // N*128 = 8388608 floats
  float* offc = O + 8388608;              // 1024*128
  float* carr = O + 8519680;              // 1024*128
  float2* powt = (float2*)(O + 8650752);  // 64*65 float2
  float2* dAf  = (float2*)(O + 8659072);  // 64 float2
  float2* fvec = (float2*)(O + 8659200);  // 64 float2

  setup_scalar_k<<<1, 64, 0, stream>>>(A_real, A_imag, inv_dt, dAf, fvec, powt);
  setup_tables_k<<<256, 256, 0, stream>>>(B_re, B_im, C_re, C_im, W_in, W_out, fvec,
                                          WinT, dBn, Ccb, WoutT);
  cvt_x_k<<<1024, 256, 0, stream>>>(x, xb);

  // K1: [u|res] = silu(x @ W_in)   (4096 blocks, 8 col tiles)
  mgemm<0, 3, 256><<<4096, 512, 0, stream>>>(xb, WinT, u_bf, sr_bf, nullptr);
  // K2: Bu = u @ dB^T (fp32 out)   (512 blocks, 1 col tile)
  mgemm<1, 0, 512><<<512, 512, 0, stream>>>(u_bf, dBn, Bu, nullptr, nullptr);
  // K3: chunked scan (fp32), emits bf16 h
  scan_sum_k<<<256, 256, 0, stream>>>(Bu, carr, dAf);
  scan_carry_k<<<1, 256, 0, stream>>>(carr, offc, powt);
  scan_emit_k<<<256, 256, 0, stream>>>(Bu, offc, h_bf, dAf);
  // K4a: g = (Re(h C^T) + D*u) * sres  (2048 blocks, 4 col tiles)
  mgemm<2, 2, 128><<<2048, 512, 0, stream>>>(h_bf, Ccb, u_bf, sr_bf, Dv);
  // K4b: out = g @ W_out           (1024 blocks, 2 col tiles)
  mgemm<3, 1, 512><<<1024, 512, 0, stream>>>(sr_bf, WoutT, O, nullptr, nullptr);
}